// Round 2
// baseline (1050.684 us; speedup 1.0000x reference)
//
#include <hip/hip_runtime.h>
#include <stdint.h>

typedef unsigned short u16;
typedef unsigned int   u32;
typedef __attribute__((ext_vector_type(4))) float f32x4;
typedef __attribute__((ext_vector_type(8))) short bf16x8;

__device__ __forceinline__ u16 f2bf(float f) {
    u32 i = __float_as_uint(f);
    u32 r = (i + 0x7fffu + ((i >> 16) & 1u)) >> 16;   // RNE
    return (u16)r;
}
__device__ __forceinline__ float bf2f(u16 u) {
    return __uint_as_float(((u32)u) << 16);
}
__device__ __forceinline__ u32 cvt2bf(float a, float b) {
    // D[15:0]=bf16(a), D[31:16]=bf16(b)
    u32 r;
    asm("v_cvt_pk_bf16_f32 %0, %1, %2" : "=v"(r) : "v"(a), "v"(b));
    return r;
}
__device__ __forceinline__ float sigmoidf_(float x) { return 1.f / (1.f + __expf(-x)); }

#define GLOAD16(g, l) __builtin_amdgcn_global_load_lds( \
    (const __attribute__((address_space(1))) void*)(g), \
    (__attribute__((address_space(3))) void*)(l), 16, 0, 0)

// ---------------------------------------------------------------- prep: degrees
__global__ void k_prep(const float* __restrict__ A, float* dis1, float* inv1,
                       float* dis2, float* inv2)
{
    int r = threadIdx.x;
    if (r >= 128) return;
    int cc = 0, cr = 0;
    for (int j = 0; j < 128; ++j) {
        if (j == r) continue;
        if (A[(j << 7) + r] != 0.f) cc++;   // column count (mp1)
        if (A[(r << 7) + j] != 0.f) cr++;   // row count (mp2, A^T)
    }
    float d1 = 1.f + (float)cc, d2 = 1.f + (float)cr;
    dis1[r] = rsqrtf(d1); inv1[r] = 1.f / d1;
    dis2[r] = rsqrtf(d2); inv2[r] = 1.f / d2;
}

// ---------------------------------------------------------------- GEMM: C = A @ B^T
// A: M x K bf16 row-major (ws), B: N x K f32 row-major (weights), C: M x N f32.
// m97 structure: 128x128 tile, BK=32, 4 waves; B reg-staged + cvt_pk -> LDS.
__global__ __launch_bounds__(256, 2)
void k_gemm_bt(const u16* __restrict__ A, const float* __restrict__ B,
               float* __restrict__ C, int M, int N, int K)
{
    __shared__ alignas(16) u16 As[128 * 32];
    __shared__ alignas(16) u16 Bs[128 * 32];
    const int tid  = threadIdx.x;
    const int lane = tid & 63;
    const int w    = tid >> 6;
    const int bm = blockIdx.y * 128, bn = blockIdx.x * 128;
    const int wm = (w >> 1) * 64,   wn = (w & 1) * 64;

    const int srow = tid >> 2, scol = (tid & 3) * 8;
    const u16* ag = A + (size_t)(bm + srow) * K + scol;
    u16* asl = As + tid * 8;
    const size_t rstep = (size_t)64 * K;

    const int srB = tid >> 1, scB = (tid & 1) * 16;
    const float* bg = B + (size_t)(bn + srB) * K + scB;
    u16* bwl = Bs + srB * 32 + scB;

    f32x4 acc[4][4] = {};
    const int lr = lane & 15, lkb = (lane >> 4) * 8;

    for (int k0 = 0; k0 < K; k0 += 32) {
        GLOAD16(ag + k0,         asl);
        GLOAD16(ag + k0 + rstep, asl + 2048);
        f32x4 b0 = *(const f32x4*)(bg + k0);
        f32x4 b1 = *(const f32x4*)(bg + k0 + 4);
        f32x4 b2 = *(const f32x4*)(bg + k0 + 8);
        f32x4 b3 = *(const f32x4*)(bg + k0 + 12);
        u32 p[8];
        p[0] = cvt2bf(b0[0], b0[1]); p[1] = cvt2bf(b0[2], b0[3]);
        p[2] = cvt2bf(b1[0], b1[1]); p[3] = cvt2bf(b1[2], b1[3]);
        p[4] = cvt2bf(b2[0], b2[1]); p[5] = cvt2bf(b2[2], b2[3]);
        p[6] = cvt2bf(b3[0], b3[1]); p[7] = cvt2bf(b3[2], b3[3]);
        *(uint4*)bwl       = *(uint4*)&p[0];
        *(uint4*)(bwl + 8) = *(uint4*)&p[4];
        __syncthreads();                     // drains vmcnt (A in LDS) + lgkm (B written)
        bf16x8 af[4], bfv[4];
        #pragma unroll
        for (int i = 0; i < 4; ++i) {
            af[i]  = *(const bf16x8*)(As + (wm + i * 16 + lr) * 32 + lkb);
            bfv[i] = *(const bf16x8*)(Bs + (wn + i * 16 + lr) * 32 + lkb);
        }
        #pragma unroll
        for (int i = 0; i < 4; ++i)
            #pragma unroll
            for (int j = 0; j < 4; ++j)
                acc[i][j] = __builtin_amdgcn_mfma_f32_16x16x32_bf16(af[i], bfv[j], acc[i][j], 0, 0, 0);
        __syncthreads();                     // protect LDS for next iter
    }

    const int orow = (lane >> 4) * 4, ocol = lane & 15;
    #pragma unroll
    for (int i = 0; i < 4; ++i) {
        #pragma unroll
        for (int j = 0; j < 4; ++j) {
            float* cp = C + (size_t)(bm + wm + i * 16 + orow) * N + (bn + wn + j * 16 + ocol);
            #pragma unroll
            for (int v = 0; v < 4; ++v)
                cp[(size_t)v * N] = acc[i][j][v];
        }
    }
}

// ---------------------------------------------------------------- GCN normalize + alpha residual
// Hout[t] = bf16( 0.05*G[t] + XW[t]*invdeg[r] + (r<128: dis[r]*sum_j Aoff[j,r]*dis[j]*XW[j,o]) + gb[o] )
template<int TR>
__global__ __launch_bounds__(256)
void k_gcn(const float* __restrict__ XW, const u16* __restrict__ G,
           const float* __restrict__ Af, const float* __restrict__ dis,
           const float* __restrict__ invdeg, const float* __restrict__ gbias,
           u16* __restrict__ Hout)
{
    int t = blockIdx.x * 256 + threadIdx.x;
    int r = t >> 12, o = t & 4095;
    float out = XW[t];
    if (r < 128) {
        out *= invdeg[r];
        float s = 0.f;
        for (int j = 0; j < 128; ++j) {
            float av = TR ? Af[(r << 7) + j] : Af[(j << 7) + r];
            float wv = ((av != 0.f) && (j != r)) ? dis[j] : 0.f;
            s = __fmaf_rn(wv, XW[(j << 12) + o], s);
        }
        out = __fmaf_rn(dis[r], s, out);
    }
    out += gbias[o];
    Hout[t] = f2bf(__fmaf_rn(0.05f, bf2f(G[t]), out));
}

// ---------------------------------------------------------------- inception + gate
template<int K_>
__device__ __forceinline__ void conv_acc(const float* __restrict__ xsb,
                                         const float* __restrict__ wfp,
                                         const float* __restrict__ wgp,
                                         float accf[16], float accg[16])
{
    for (int c = 0; c < 32; ++c) {
        float xwin[32];
        const float* xr = xsb + c * 144;
        #pragma unroll
        for (int q = 0; q < 8; ++q) {
            f32x4 v = *(const f32x4*)(xr + q * 4);
            xwin[q * 4 + 0] = v[0]; xwin[q * 4 + 1] = v[1];
            xwin[q * 4 + 2] = v[2]; xwin[q * 4 + 3] = v[3];
        }
        float wfj[K_], wgj[K_];
        const float* wfc = wfp + c * K_;
        const float* wgc = wgp + c * K_;
        #pragma unroll
        for (int j = 0; j < K_; ++j) { wfj[j] = wfc[j]; wgj[j] = wgc[j]; }
        #pragma unroll
        for (int li = 0; li < 16; ++li) {
            #pragma unroll
            for (int j = 0; j < K_; ++j) {
                float xv = xwin[li + 8 - (K_ - 1) + 2 * j];
                accf[li] = __fmaf_rn(xv, wfj[j], accf[li]);
                accg[li] = __fmaf_rn(xv, wgj[j], accg[li]);
            }
        }
    }
}

__global__ __launch_bounds__(256)
void k_incep(const float* __restrict__ x,
             const float* __restrict__ fw2p, const float* __restrict__ fw3p,
             const float* __restrict__ fw6p, const float* __restrict__ fw7p,
             const float* __restrict__ fb2p, const float* __restrict__ fb3p,
             const float* __restrict__ fb6p, const float* __restrict__ fb7p,
             const float* __restrict__ gw2p, const float* __restrict__ gw3p,
             const float* __restrict__ gw6p, const float* __restrict__ gw7p,
             const float* __restrict__ gb2p, const float* __restrict__ gb3p,
             const float* __restrict__ gb6p, const float* __restrict__ gb7p,
             u16* __restrict__ G)
{
    __shared__ alignas(16) float xs[32 * 144];       // +8 guard each side along L
    __shared__ float wfl[4640], wgl[4640];           // padded (32k+1) per oo
    __shared__ float fbl[32], gbl[32];
    const int tid = threadIdx.x;
    const int b = blockIdx.x >> 7, n = blockIdx.x & 127;

    for (int i = tid; i < 32 * 144; i += 256) xs[i] = 0.f;
    for (int g = tid; g < 4608; g += 256) {
        int rel, k, woff;
        const float *pf, *pg;
        if (g < 512)       { rel = g;        k = 2; woff = 0;    pf = fw2p; pg = gw2p; }
        else if (g < 1280) { rel = g - 512;  k = 3; woff = 520;  pf = fw3p; pg = gw3p; }
        else if (g < 2816) { rel = g - 1280; k = 6; woff = 1296; pf = fw6p; pg = gw6p; }
        else               { rel = g - 2816; k = 7; woff = 2840; pf = fw7p; pg = gw7p; }
        int ck = 32 * k;
        int oo = rel / ck, rem = rel % ck;
        int dst = woff + oo * (ck + 1) + rem;
        wfl[dst] = pf[rel];
        wgl[dst] = pg[rel];
    }
    if (tid < 32) {
        int br = tid >> 3, oo = tid & 7;
        const float* pf = br == 0 ? fb2p : br == 1 ? fb3p : br == 2 ? fb6p : fb7p;
        const float* pg = br == 0 ? gb2p : br == 1 ? gb3p : br == 2 ? gb6p : gb7p;
        fbl[tid] = pf[oo]; gbl[tid] = pg[oo];
    }
    __syncthreads();
    // stage x[b,:,n,:] into guarded f32 LDS
    const float* xb = x + (size_t)b * 524288 + n * 128;
    for (int p = 0; p < 4; ++p) {
        int chunk = p * 256 + tid;
        int c = chunk >> 5, l4 = (chunk & 31) * 4;
        *(f32x4*)&xs[c * 144 + 8 + l4] = *(const f32x4*)(xb + (size_t)c * 16384 + l4);
    }
    __syncthreads();

    const int w = tid >> 6, lane = tid & 63;
    const int oo = lane >> 3, l0 = (lane & 7) * 16;
    const int o = w * 8 + oo;                    // wave-uniform branch (no divergence)
    float accf[16], accg[16];
    float fbv = fbl[o], gbv = gbl[o];
    #pragma unroll
    for (int i = 0; i < 16; ++i) { accf[i] = fbv; accg[i] = gbv; }
    const float* xsb = xs + l0;
    switch (w) {
        case 0:  conv_acc<2>(xsb, wfl + 0    + oo * 65,  wgl + 0    + oo * 65,  accf, accg); break;
        case 1:  conv_acc<3>(xsb, wfl + 520  + oo * 97,  wgl + 520  + oo * 97,  accf, accg); break;
        case 2:  conv_acc<6>(xsb, wfl + 1296 + oo * 193, wgl + 1296 + oo * 193, accf, accg); break;
        default: conv_acc<7>(xsb, wfl + 2840 + oo * 225, wgl + 2840 + oo * 225, accf, accg); break;
    }
    u16 outs[16];
    #pragma unroll
    for (int i = 0; i < 16; ++i)
        outs[i] = f2bf(tanhf(accf[i]) * sigmoidf_(accg[i]));
    u16* Gp = G + ((size_t)(b * 32 + o) * 128 + n) * 128 + l0;
    uint4 u0, u1;
    u0.x = outs[0] | ((u32)outs[1] << 16);  u0.y = outs[2] | ((u32)outs[3] << 16);
    u0.z = outs[4] | ((u32)outs[5] << 16);  u0.w = outs[6] | ((u32)outs[7] << 16);
    u1.x = outs[8] | ((u32)outs[9] << 16);  u1.y = outs[10] | ((u32)outs[11] << 16);
    u1.z = outs[12] | ((u32)outs[13] << 16); u1.w = outs[14] | ((u32)outs[15] << 16);
    *(uint4*)Gp = u0; *(uint4*)(Gp + 8) = u1;
}

// ---------------------------------------------------------------- skip projection
__global__ __launch_bounds__(256)
void k_skip(const u16* __restrict__ G, const float* __restrict__ xskip,
            const float* __restrict__ sw, const float* __restrict__ sb,
            float* __restrict__ outp)
{
    __shared__ alignas(16) u16 Gs[4096];
    __shared__ float swl[64 * 33];
    __shared__ float sbl[64];
    const int tid = threadIdx.x;
    const int b = blockIdx.x >> 7, n = blockIdx.x & 127;
    const u16* gb_ = G + (size_t)b * 524288 + n * 128;
    for (int p = 0; p < 2; ++p) {
        int chunk = p * 256 + tid, c = chunk >> 4, l8 = (chunk & 15) * 8;
        *(uint4*)&Gs[c * 128 + l8] = *(const uint4*)(gb_ + (size_t)c * 16384 + l8);
    }
    for (int i = tid; i < 2048; i += 256) swl[(i >> 5) * 33 + (i & 31)] = sw[i];
    if (tid < 64) sbl[tid] = sb[tid];
    __syncthreads();
    const int sg = (tid & 15) * 4, l0 = (tid >> 4) * 8;
    float acc[4][8];
    #pragma unroll
    for (int si = 0; si < 4; ++si) {
        float bv = sbl[sg + si];
        #pragma unroll
        for (int li = 0; li < 8; ++li) acc[si][li] = bv;
    }
    for (int c = 0; c < 32; ++c) {
        uint4 gv = *(const uint4*)&Gs[c * 128 + l0];
        float g[8];
        g[0] = __uint_as_float(gv.x << 16); g[1] = __uint_as_float(gv.x & 0xffff0000u);
        g[2] = __uint_as_float(gv.y << 16); g[3] = __uint_as_float(gv.y & 0xffff0000u);
        g[4] = __uint_as_float(gv.z << 16); g[5] = __uint_as_float(gv.z & 0xffff0000u);
        g[6] = __uint_as_float(gv.w << 16); g[7] = __uint_as_float(gv.w & 0xffff0000u);
        #pragma unroll
        for (int si = 0; si < 4; ++si) {
            float wv = swl[(sg + si) * 33 + c];
            #pragma unroll
            for (int li = 0; li < 8; ++li) acc[si][li] = __fmaf_rn(g[li], wv, acc[si][li]);
        }
    }
    #pragma unroll
    for (int si = 0; si < 4; ++si) {
        size_t e = ((size_t)(b * 64 + sg + si) * 128 + n) * 128 + l0;
        f32x4 x0 = *(const f32x4*)(xskip + e);
        f32x4 x1 = *(const f32x4*)(xskip + e + 4);
        f32x4 r0, r1;
        r0[0] = acc[si][0] + x0[0]; r0[1] = acc[si][1] + x0[1];
        r0[2] = acc[si][2] + x0[2]; r0[3] = acc[si][3] + x0[3];
        r1[0] = acc[si][4] + x1[0]; r1[1] = acc[si][5] + x1[1];
        r1[2] = acc[si][6] + x1[2]; r1[3] = acc[si][7] + x1[3];
        *(f32x4*)(outp + e)     = r0;
        *(f32x4*)(outp + e + 4) = r1;
    }
}

// ---------------------------------------------------------------- 96->32 channel mix
template<int ACCUM>
__global__ __launch_bounds__(256)
void k_mix(const u16* __restrict__ G, const u16* __restrict__ H1,
           const u16* __restrict__ H2, const float* __restrict__ mw,
           const float* __restrict__ mb, float* __restrict__ OUT)
{
    __shared__ alignas(16) u16 Gs[4096], H1s[4096], H2s[4096];
    __shared__ float mwl[32 * 97];
    __shared__ float mbl[32];
    const int tid = threadIdx.x;
    const int b = blockIdx.x >> 7, xn = blockIdx.x & 127;
    size_t base = (size_t)b * 524288 + xn * 128;
    for (int p = 0; p < 2; ++p) {
        int chunk = p * 256 + tid, c = chunk >> 4, l8 = (chunk & 15) * 8;
        size_t src = base + (size_t)c * 16384 + l8;
        *(uint4*)&Gs[c * 128 + l8]  = *(const uint4*)(G + src);
        *(uint4*)&H1s[c * 128 + l8] = *(const uint4*)(H1 + src);
        *(uint4*)&H2s[c * 128 + l8] = *(const uint4*)(H2 + src);
    }
    for (int i = tid; i < 3072; i += 256) mwl[(i / 96) * 97 + (i % 96)] = mw[i];
    if (tid < 32) mbl[tid] = mb[tid];
    __syncthreads();
    const int og = (tid & 7) * 4, l0 = (tid >> 3) * 4;
    float acc[4][4];
    #pragma unroll
    for (int oi = 0; oi < 4; ++oi) {
        float bv = mbl[og + oi];
        acc[oi][0] = bv; acc[oi][1] = bv; acc[oi][2] = bv; acc[oi][3] = bv;
    }
    for (int c = 0; c < 32; ++c) {
        uint2 ga = *(const uint2*)&Gs[c * 128 + l0];
        uint2 h1 = *(const uint2*)&H1s[c * 128 + l0];
        uint2 h2 = *(const uint2*)&H2s[c * 128 + l0];
        float gv[4], v1[4], v2[4];
        gv[0] = __uint_as_float(ga.x << 16); gv[1] = __uint_as_float(ga.x & 0xffff0000u);
        gv[2] = __uint_as_float(ga.y << 16); gv[3] = __uint_as_float(ga.y & 0xffff0000u);
        v1[0] = __uint_as_float(h1.x << 16); v1[1] = __uint_as_float(h1.x & 0xffff0000u);
        v1[2] = __uint_as_float(h1.y << 16); v1[3] = __uint_as_float(h1.y & 0xffff0000u);
        v2[0] = __uint_as_float(h2.x << 16); v2[1] = __uint_as_float(h2.x & 0xffff0000u);
        v2[2] = __uint_as_float(h2.y << 16); v2[3] = __uint_as_float(h2.y & 0xffff0000u);
        #pragma unroll
        for (int oi = 0; oi < 4; ++oi) {
            int o = og + oi;
            float w0 = mwl[o * 97 + c], w1 = mwl[o * 97 + 32 + c], w2 = mwl[o * 97 + 64 + c];
            #pragma unroll
            for (int li = 0; li < 4; ++li)
                acc[oi][li] += gv[li] * w0 + v1[li] * w1 + v2[li] * w2;
        }
    }
    #pragma unroll
    for (int oi = 0; oi < 4; ++oi) {
        size_t e = ((size_t)(b * 32 + og + oi) * 128 + xn) * 128 + l0;
        f32x4 v; v[0] = acc[oi][0]; v[1] = acc[oi][1]; v[2] = acc[oi][2]; v[3] = acc[oi][3];
        if (ACCUM) { f32x4 old = *(const f32x4*)(OUT + e); v += old; }
        *(f32x4*)(OUT + e) = v;
    }
}

// ---------------------------------------------------------------- LayerNorm (2-stage, deterministic)
__global__ __launch_bounds__(256)
void k_lnsum(const float* __restrict__ OUT, const float* __restrict__ xin,
             float* __restrict__ partial)
{
    const int tid = threadIdx.x;
    const int b = blockIdx.x >> 7, chunk = blockIdx.x & 127;
    size_t base = (size_t)b * 524288 + (size_t)chunk * 4096;
    float s = 0.f, ss = 0.f;
    #pragma unroll
    for (int q = 0; q < 4; ++q) {
        size_t e = base + q * 1024 + tid * 4;
        f32x4 ov = *(const f32x4*)(OUT + e);
        f32x4 xv = *(const f32x4*)(xin + e);
        float y0 = ov[0] + xv[0];
        float y1 = ov[1] + xv[1];
        float y2 = ov[2] + xv[2];
        float y3 = ov[3] + xv[3];
        s += y0 + y1 + y2 + y3;
        ss += y0 * y0 + y1 * y1 + y2 * y2 + y3 * y3;
    }
    #pragma unroll
    for (int o = 32; o > 0; o >>= 1) {
        s  += __shfl_down(s,  o, 64);
        ss += __shfl_down(ss, o, 64);
    }
    __shared__ float sred[8];
    int w = tid >> 6;
    if ((tid & 63) == 0) { sred[w * 2] = s; sred[w * 2 + 1] = ss; }
    __syncthreads();
    if (tid == 0) {
        partial[blockIdx.x * 2]     = sred[0] + sred[2] + sred[4] + sred[6];
        partial[blockIdx.x * 2 + 1] = sred[1] + sred[3] + sred[5] + sred[7];
    }
}

__global__ __launch_bounds__(256)
void k_lnnorm(const float* __restrict__ OUT, const float* __restrict__ xin,
              const float* __restrict__ partial, const int* __restrict__ idxp,
              const float* __restrict__ lnw, const float* __restrict__ lnb,
              float* __restrict__ outx)
{
    const int tid = threadIdx.x;
    const int b = blockIdx.x >> 7, chunk = blockIdx.x & 127;
    float s = 0.f, ss = 0.f;
    if (tid < 128) {
        s  = partial[(b * 128 + tid) * 2];
        ss = partial[(b * 128 + tid) * 2 + 1];
    }
    #pragma unroll
    for (int o = 32; o > 0; o >>= 1) {
        s  += __shfl_down(s,  o, 64);
        ss += __shfl_down(ss, o, 64);
    }
    __shared__ float sred[4];
    __shared__ float mv[2];
    if ((tid & 63) == 0 && tid < 128) { sred[(tid >> 6) * 2] = s; sred[(tid >> 6) * 2 + 1] = ss; }
    __syncthreads();
    if (tid == 0) {
        float S = sred[0] + sred[2], SS = sred[1] + sred[3];
        float mean = S * (1.f / 524288.f);
        float var = SS * (1.f / 524288.f) - mean * mean;
        mv[0] = mean; mv[1] = rsqrtf(var + 1e-5f);
    }
    __syncthreads();
    const float mean = mv[0], rstd = mv[1];
    #pragma unroll
    for (int q = 0; q < 4; ++q) {
        int ib = chunk * 4096 + q * 1024 + tid * 4;   // in-batch flat index (4 consecutive)
        size_t e = (size_t)b * 524288 + ib;
        f32x4 ov = *(const f32x4*)(OUT + e);
        f32x4 xv = *(const f32x4*)(xin + e);
        int c = ib >> 14, xn = (ib >> 7) & 127, l = ib & 127;
        int ix = idxp[xn];
        size_t we = ((size_t)c * 128 + ix) * 128 + l;
        f32x4 wv = *(const f32x4*)(lnw + we);
        f32x4 bv = *(const f32x4*)(lnb + we);
        f32x4 r;
        #pragma unroll
        for (int j = 0; j < 4; ++j) {
            float y = ov[j] + xv[j];
            r[j] = (y - mean) * rstd * wv[j] + bv[j];
        }
        *(f32x4*)(outx + e) = r;
    }
}

// ---------------------------------------------------------------- launcher
extern "C" void kernel_launch(void* const* d_in, const int* in_sizes, int n_in,
                              void* d_out, int out_size, void* d_ws, size_t ws_size,
                              hipStream_t stream)
{
    (void)in_sizes; (void)n_in; (void)out_size; (void)ws_size;
    const float* x      = (const float*)d_in[0];
    const float* xskip  = (const float*)d_in[1];
    const float* A      = (const float*)d_in[2];
    const int*   idxp   = (const int*)d_in[3];
    const float* fw2p = (const float*)d_in[4];  const float* fb2p = (const float*)d_in[5];
    const float* fw3p = (const float*)d_in[6];  const float* fb3p = (const float*)d_in[7];
    const float* fw6p = (const float*)d_in[8];  const float* fb6p = (const float*)d_in[9];
    const float* fw7p = (const float*)d_in[10]; const float* fb7p = (const float*)d_in[11];
    const float* gw2p = (const float*)d_in[12]; const float* gb2p = (const float*)d_in[13];
    const float* gw3p = (const float*)d_in[14]; const float* gb3p = (const float*)d_in[15];
    const float* gw6p = (const float*)d_in[16]; const float* gb6p = (const float*)d_in[17];
    const float* gw7p = (const float*)d_in[18]; const float* gb7p = (const float*)d_in[19];
    const float* sw   = (const float*)d_in[20]; const float* sb   = (const float*)d_in[21];
    const float* mp1_gw = (const float*)d_in[22]; const float* mp1_gb = (const float*)d_in[23];
    const float* mp1_mw = (const float*)d_in[24]; const float* mp1_mb = (const float*)d_in[25];
    const float* mp2_gw = (const float*)d_in[26]; const float* mp2_gb = (const float*)d_in[27];
    const float* mp2_mw = (const float*)d_in[28]; const float* mp2_mb = (const float*)d_in[29];
    const float* lnw = (const float*)d_in[30]; const float* lnb = (const float*)d_in[31];

    char* wsb = (char*)d_ws;
    u16*   G   = (u16*)(wsb);                       // 16,777,216 B
    float* T1  = (float*)(wsb + 16777216);          // 33,554,432 B (XW)
    u16*   H1  = (u16*)(wsb + 50331648);            // 16,777,216 B
    u16*   H2  = (u16*)(wsb + 67108864);            // 16,777,216 B
    float* OUT = (float*)(wsb + 83886080);          // 33,554,432 B
    float* part= (float*)(wsb + 117440512);         // 16,384 B
    float* dd  = (float*)(wsb + 117456896);         // 2,048 B
    float *dis1 = dd, *inv1 = dd + 128, *dis2 = dd + 256, *inv2 = dd + 384;

    float* out_x  = (float*)d_out;
    float* out_sk = out_x + 8388608;

    k_prep<<<1, 128, 0, stream>>>(A, dis1, inv1, dis2, inv2);
    k_incep<<<2048, 256, 0, stream>>>(x, fw2p, fw3p, fw6p, fw7p, fb2p, fb3p, fb6p, fb7p,
                                      gw2p, gw3p, gw6p, gw7p, gb2p, gb3p, gb6p, gb7p, G);
    k_skip<<<2048, 256, 0, stream>>>(G, xskip, sw, sb, out_sk);

    dim3 gg(32, 16);
    // mixprop 1 (A)
    k_gemm_bt<<<gg, 256, 0, stream>>>(G, mp1_gw, T1, 2048, 4096, 4096);
    k_gcn<0><<<32768, 256, 0, stream>>>(T1, G, A, dis1, inv1, mp1_gb, H1);
    k_gemm_bt<<<gg, 256, 0, stream>>>(H1, mp1_gw + (size_t)16777216, T1, 2048, 4096, 4096);
    k_gcn<0><<<32768, 256, 0, stream>>>(T1, G, A, dis1, inv1, mp1_gb + 4096, H2);
    k_mix<0><<<2048, 256, 0, stream>>>(G, H1, H2, mp1_mw, mp1_mb, OUT);
    // mixprop 2 (A^T)
    k_gemm_bt<<<gg, 256, 0, stream>>>(G, mp2_gw, T1, 2048, 4096, 4096);
    k_gcn<1><<<32768, 256, 0, stream>>>(T1, G, A, dis2, inv2, mp2_gb, H1);
    k_gemm_bt<<<gg, 256, 0, stream>>>(H1, mp2_gw + (size_t)16777216, T1, 2048, 4096, 4096);
    k_gcn<1><<<32768, 256, 0, stream>>>(T1, G, A, dis2, inv2, mp2_gb + 4096, H2);
    k_mix<1><<<2048, 256, 0, stream>>>(G, H1, H2, mp2_mw, mp2_mb, OUT);
    // layernorm (+ x residual) -> out
    k_lnsum<<<2048, 256, 0, stream>>>(OUT, x, part);
    k_lnnorm<<<2048, 256, 0, stream>>>(OUT, x, part, idxp, lnw, lnb, out_x);
}

// Round 3
// 888.047 us; speedup vs baseline: 1.1831x; 1.1831x over previous
//
#include <hip/hip_runtime.h>
#include <stdint.h>

typedef unsigned short u16;
typedef unsigned int   u32;
typedef __attribute__((ext_vector_type(4))) float f32x4;
typedef __attribute__((ext_vector_type(8))) short bf16x8;

__device__ __forceinline__ u16 f2bf(float f) {
    u32 i = __float_as_uint(f);
    u32 r = (i + 0x7fffu + ((i >> 16) & 1u)) >> 16;   // RNE
    return (u16)r;
}
__device__ __forceinline__ float bf2f(u16 u) {
    return __uint_as_float(((u32)u) << 16);
}
__device__ __forceinline__ u32 cvt2bf(float a, float b) {
    // D[15:0]=bf16(a), D[31:16]=bf16(b), RNE
    u32 r;
    asm("v_cvt_pk_bf16_f32 %0, %1, %2" : "=v"(r) : "v"(a), "v"(b));
    return r;
}
__device__ __forceinline__ float sigmoidf_(float x) { return 1.f / (1.f + __expf(-x)); }

#define GLOAD16(g, l) __builtin_amdgcn_global_load_lds( \
    (const __attribute__((address_space(1))) void*)(g), \
    (__attribute__((address_space(3))) void*)(l), 16, 0, 0)

// ---------------------------------------------------------------- prep: degrees
__global__ void k_prep(const float* __restrict__ A, float* dis1, float* inv1,
                       float* dis2, float* inv2)
{
    int r = threadIdx.x;
    if (r >= 128) return;
    int cc = 0, cr = 0;
    for (int j = 0; j < 128; ++j) {
        if (j == r) continue;
        if (A[(j << 7) + r] != 0.f) cc++;   // column count (mp1)
        if (A[(r << 7) + j] != 0.f) cr++;   // row count (mp2, A^T)
    }
    float d1 = 1.f + (float)cc, d2 = 1.f + (float)cr;
    dis1[r] = rsqrtf(d1); inv1[r] = 1.f / d1;
    dis2[r] = rsqrtf(d2); inv2[r] = 1.f / d2;
}

// ---------------------------------------------------------------- weight f32 -> bf16 (streaming)
__global__ __launch_bounds__(256)
void k_wcvt(const float* __restrict__ W, u16* __restrict__ Wb)
{
    size_t e = ((size_t)blockIdx.x * 256 + threadIdx.x) * 8;   // grid 8192 -> 16M elems
    f32x4 a = *(const f32x4*)(W + e);
    f32x4 b = *(const f32x4*)(W + e + 4);
    uint4 r;
    r.x = cvt2bf(a[0], a[1]); r.y = cvt2bf(a[2], a[3]);
    r.z = cvt2bf(b[0], b[1]); r.w = cvt2bf(b[2], b[3]);
    *(uint4*)(Wb + e) = r;
}

// ---------------------------------------------------------------- GEMM: C = A @ B^T
// A: M x K bf16, B: N x K bf16, C: M x N f32. m97 structure:
// 128x128 tile, BK=32, 4 waves, pure global_load_lds staging.
__global__ __launch_bounds__(256, 2)
void k_gemm_bt(const u16* __restrict__ A, const u16* __restrict__ B,
               float* __restrict__ C, int M, int N, int K)
{
    __shared__ alignas(16) u16 As[128 * 32];
    __shared__ alignas(16) u16 Bs[128 * 32];
    const int tid  = threadIdx.x;
    const int lane = tid & 63;
    const int w    = tid >> 6;
    const int bm = blockIdx.y * 128, bn = blockIdx.x * 128;
    const int wm = (w >> 1) * 64,   wn = (w & 1) * 64;

    const int srow = tid >> 2, scol = (tid & 3) * 8;
    const u16* ag = A + (size_t)(bm + srow) * K + scol;
    const u16* bg = B + (size_t)(bn + srow) * K + scol;
    u16* asl = As + tid * 8;
    u16* bsl = Bs + tid * 8;
    const size_t rstep = (size_t)64 * K;

    f32x4 acc[4][4] = {};
    const int lr = lane & 15, lkb = (lane >> 4) * 8;

    for (int k0 = 0; k0 < K; k0 += 32) {
        GLOAD16(ag + k0,         asl);
        GLOAD16(ag + k0 + rstep, asl + 2048);
        GLOAD16(bg + k0,         bsl);
        GLOAD16(bg + k0 + rstep, bsl + 2048);
        __syncthreads();                     // drains vmcnt: tiles ready
        bf16x8 af[4], bfv[4];
        #pragma unroll
        for (int i = 0; i < 4; ++i) {
            af[i]  = *(const bf16x8*)(As + (wm + i * 16 + lr) * 32 + lkb);
            bfv[i] = *(const bf16x8*)(Bs + (wn + i * 16 + lr) * 32 + lkb);
        }
        #pragma unroll
        for (int i = 0; i < 4; ++i)
            #pragma unroll
            for (int j = 0; j < 4; ++j)
                acc[i][j] = __builtin_amdgcn_mfma_f32_16x16x32_bf16(af[i], bfv[j], acc[i][j], 0, 0, 0);
        __syncthreads();                     // protect LDS for next iter
    }

    const int orow = (lane >> 4) * 4, ocol = lane & 15;
    #pragma unroll
    for (int i = 0; i < 4; ++i) {
        #pragma unroll
        for (int j = 0; j < 4; ++j) {
            float* cp = C + (size_t)(bm + wm + i * 16 + orow) * N + (bn + wn + j * 16 + ocol);
            #pragma unroll
            for (int v = 0; v < 4; ++v)
                cp[(size_t)v * N] = acc[i][j][v];
        }
    }
}

// ---------------------------------------------------------------- GCN normalize + alpha residual
// Hout = bf16( 0.05*G + XW*invdeg[r] + (r<128: dis[r]*sum_j Aoff*dis[j]*XW[j]) + gb[o] )
template<int TR>
__global__ __launch_bounds__(256)
void k_gcn(const float* __restrict__ XW, const u16* __restrict__ G,
           const float* __restrict__ Af, const float* __restrict__ dis,
           const float* __restrict__ invdeg, const float* __restrict__ gbias,
           u16* __restrict__ Hout)
{
    int t4 = blockIdx.x * 256 + threadIdx.x;       // grid 8192 -> 2M threads, 4 elems each
    int r = t4 >> 10, og = (t4 & 1023) << 2;
    size_t e = ((size_t)r << 12) + og;
    f32x4 out = *(const f32x4*)(XW + e);
    if (r < 128) {
        float iv = invdeg[r];
        f32x4 s = {0.f, 0.f, 0.f, 0.f};
        for (int j = 0; j < 128; ++j) {
            float av = TR ? Af[(r << 7) + j] : Af[(j << 7) + r];
            float wv = ((av != 0.f) && (j != r)) ? dis[j] : 0.f;
            f32x4 xv = *(const f32x4*)(XW + ((size_t)j << 12) + og);
            #pragma unroll
            for (int q = 0; q < 4; ++q) s[q] = __fmaf_rn(wv, xv[q], s[q]);
        }
        float dr = dis[r];
        #pragma unroll
        for (int q = 0; q < 4; ++q) out[q] = __fmaf_rn(dr, s[q], out[q] * iv);
    }
    f32x4 gb4 = *(const f32x4*)(gbias + og);
    uint2 gv = *(const uint2*)(G + e);
    float g0 = __uint_as_float(gv.x << 16), g1 = __uint_as_float(gv.x & 0xffff0000u);
    float g2 = __uint_as_float(gv.y << 16), g3 = __uint_as_float(gv.y & 0xffff0000u);
    float y0 = __fmaf_rn(0.05f, g0, out[0] + gb4[0]);
    float y1 = __fmaf_rn(0.05f, g1, out[1] + gb4[1]);
    float y2 = __fmaf_rn(0.05f, g2, out[2] + gb4[2]);
    float y3 = __fmaf_rn(0.05f, g3, out[3] + gb4[3]);
    uint2 rr;
    rr.x = cvt2bf(y0, y1);
    rr.y = cvt2bf(y2, y3);
    *(uint2*)(Hout + e) = rr;
}

// ---------------------------------------------------------------- inception + gate
template<int K_>
__device__ __forceinline__ void conv_acc(const float* __restrict__ xsb,
                                         const float* __restrict__ wfp,
                                         const float* __restrict__ wgp,
                                         float accf[16], float accg[16])
{
    for (int c = 0; c < 32; ++c) {
        float xwin[32];
        const float* xr = xsb + c * 144;
        #pragma unroll
        for (int q = 0; q < 8; ++q) {
            f32x4 v = *(const f32x4*)(xr + q * 4);
            xwin[q * 4 + 0] = v[0]; xwin[q * 4 + 1] = v[1];
            xwin[q * 4 + 2] = v[2]; xwin[q * 4 + 3] = v[3];
        }
        float wfj[K_], wgj[K_];
        const float* wfc = wfp + c * K_;
        const float* wgc = wgp + c * K_;
        #pragma unroll
        for (int j = 0; j < K_; ++j) { wfj[j] = wfc[j]; wgj[j] = wgc[j]; }
        #pragma unroll
        for (int li = 0; li < 16; ++li) {
            #pragma unroll
            for (int j = 0; j < K_; ++j) {
                float xv = xwin[li + 8 - (K_ - 1) + 2 * j];
                accf[li] = __fmaf_rn(xv, wfj[j], accf[li]);
                accg[li] = __fmaf_rn(xv, wgj[j], accg[li]);
            }
        }
    }
}

__global__ __launch_bounds__(256)
void k_incep(const float* __restrict__ x,
             const float* __restrict__ fw2p, const float* __restrict__ fw3p,
             const float* __restrict__ fw6p, const float* __restrict__ fw7p,
             const float* __restrict__ fb2p, const float* __restrict__ fb3p,
             const float* __restrict__ fb6p, const float* __restrict__ fb7p,
             const float* __restrict__ gw2p, const float* __restrict__ gw3p,
             const float* __restrict__ gw6p, const float* __restrict__ gw7p,
             const float* __restrict__ gb2p, const float* __restrict__ gb3p,
             const float* __restrict__ gb6p, const float* __restrict__ gb7p,
             u16* __restrict__ G)
{
    __shared__ alignas(16) float xs[32 * 144];       // +8 guard each side along L
    __shared__ float wfl[4640], wgl[4640];           // padded (32k+1) per oo
    __shared__ float fbl[32], gbl[32];
    const int tid = threadIdx.x;
    const int b = blockIdx.x >> 7, n = blockIdx.x & 127;

    for (int i = tid; i < 32 * 144; i += 256) xs[i] = 0.f;
    for (int g = tid; g < 4608; g += 256) {
        int rel, k, woff;
        const float *pf, *pg;
        if (g < 512)       { rel = g;        k = 2; woff = 0;    pf = fw2p; pg = gw2p; }
        else if (g < 1280) { rel = g - 512;  k = 3; woff = 520;  pf = fw3p; pg = gw3p; }
        else if (g < 2816) { rel = g - 1280; k = 6; woff = 1296; pf = fw6p; pg = gw6p; }
        else               { rel = g - 2816; k = 7; woff = 2840; pf = fw7p; pg = gw7p; }
        int ck = 32 * k;
        int oo = rel / ck, rem = rel % ck;
        int dst = woff + oo * (ck + 1) + rem;
        wfl[dst] = pf[rel];
        wgl[dst] = pg[rel];
    }
    if (tid < 32) {
        int br = tid >> 3, oo = tid & 7;
        const float* pf = br == 0 ? fb2p : br == 1 ? fb3p : br == 2 ? fb6p : fb7p;
        const float* pg = br == 0 ? gb2p : br == 1 ? gb3p : br == 2 ? gb6p : gb7p;
        fbl[tid] = pf[oo]; gbl[tid] = pg[oo];
    }
    __syncthreads();
    // stage x[b,:,n,:] into guarded f32 LDS
    const float* xb = x + (size_t)b * 524288 + n * 128;
    for (int p = 0; p < 4; ++p) {
        int chunk = p * 256 + tid;
        int c = chunk >> 5, l4 = (chunk & 31) * 4;
        *(f32x4*)&xs[c * 144 + 8 + l4] = *(const f32x4*)(xb + (size_t)c * 16384 + l4);
    }
    __syncthreads();

    const int w = tid >> 6, lane = tid & 63;
    const int oo = lane >> 3, l0 = (lane & 7) * 16;
    const int o = w * 8 + oo;                    // wave-uniform branch (no divergence)
    float accf[16], accg[16];
    float fbv = fbl[o], gbv = gbl[o];
    #pragma unroll
    for (int i = 0; i < 16; ++i) { accf[i] = fbv; accg[i] = gbv; }
    const float* xsb = xs + l0;
    switch (w) {
        case 0:  conv_acc<2>(xsb, wfl + 0    + oo * 65,  wgl + 0    + oo * 65,  accf, accg); break;
        case 1:  conv_acc<3>(xsb, wfl + 520  + oo * 97,  wgl + 520  + oo * 97,  accf, accg); break;
        case 2:  conv_acc<6>(xsb, wfl + 1296 + oo * 193, wgl + 1296 + oo * 193, accf, accg); break;
        default: conv_acc<7>(xsb, wfl + 2840 + oo * 225, wgl + 2840 + oo * 225, accf, accg); break;
    }
    u16 outs[16];
    #pragma unroll
    for (int i = 0; i < 16; ++i)
        outs[i] = f2bf(tanhf(accf[i]) * sigmoidf_(accg[i]));
    u16* Gp = G + ((size_t)(b * 32 + o) * 128 + n) * 128 + l0;
    uint4 u0, u1;
    u0.x = outs[0] | ((u32)outs[1] << 16);  u0.y = outs[2] | ((u32)outs[3] << 16);
    u0.z = outs[4] | ((u32)outs[5] << 16);  u0.w = outs[6] | ((u32)outs[7] << 16);
    u1.x = outs[8] | ((u32)outs[9] << 16);  u1.y = outs[10] | ((u32)outs[11] << 16);
    u1.z = outs[12] | ((u32)outs[13] << 16); u1.w = outs[14] | ((u32)outs[15] << 16);
    *(uint4*)Gp = u0; *(uint4*)(Gp + 8) = u1;
}

// ---------------------------------------------------------------- skip projection
__global__ __launch_bounds__(256)
void k_skip(const u16* __restrict__ G, const float* __restrict__ xskip,
            const float* __restrict__ sw, const float* __restrict__ sb,
            float* __restrict__ outp)
{
    __shared__ alignas(16) u16 Gs[4096];
    __shared__ float swl[64 * 33];
    __shared__ float sbl[64];
    const int tid = threadIdx.x;
    const int b = blockIdx.x >> 7, n = blockIdx.x & 127;
    const u16* gb_ = G + (size_t)b * 524288 + n * 128;
    for (int p = 0; p < 2; ++p) {
        int chunk = p * 256 + tid, c = chunk >> 4, l8 = (chunk & 15) * 8;
        *(uint4*)&Gs[c * 128 + l8] = *(const uint4*)(gb_ + (size_t)c * 16384 + l8);
    }
    for (int i = tid; i < 2048; i += 256) swl[(i >> 5) * 33 + (i & 31)] = sw[i];
    if (tid < 64) sbl[tid] = sb[tid];
    __syncthreads();
    const int sg = (tid & 15) * 4, l0 = (tid >> 4) * 8;
    float acc[4][8];
    #pragma unroll
    for (int si = 0; si < 4; ++si) {
        float bv = sbl[sg + si];
        #pragma unroll
        for (int li = 0; li < 8; ++li) acc[si][li] = bv;
    }
    for (int c = 0; c < 32; ++c) {
        uint4 gv = *(const uint4*)&Gs[c * 128 + l0];
        float g[8];
        g[0] = __uint_as_float(gv.x << 16); g[1] = __uint_as_float(gv.x & 0xffff0000u);
        g[2] = __uint_as_float(gv.y << 16); g[3] = __uint_as_float(gv.y & 0xffff0000u);
        g[4] = __uint_as_float(gv.z << 16); g[5] = __uint_as_float(gv.z & 0xffff0000u);
        g[6] = __uint_as_float(gv.w << 16); g[7] = __uint_as_float(gv.w & 0xffff0000u);
        #pragma unroll
        for (int si = 0; si < 4; ++si) {
            float wv = swl[(sg + si) * 33 + c];
            #pragma unroll
            for (int li = 0; li < 8; ++li) acc[si][li] = __fmaf_rn(g[li], wv, acc[si][li]);
        }
    }
    #pragma unroll
    for (int si = 0; si < 4; ++si) {
        size_t e = ((size_t)(b * 64 + sg + si) * 128 + n) * 128 + l0;
        f32x4 x0 = *(const f32x4*)(xskip + e);
        f32x4 x1 = *(const f32x4*)(xskip + e + 4);
        f32x4 r0, r1;
        r0[0] = acc[si][0] + x0[0]; r0[1] = acc[si][1] + x0[1];
        r0[2] = acc[si][2] + x0[2]; r0[3] = acc[si][3] + x0[3];
        r1[0] = acc[si][4] + x1[0]; r1[1] = acc[si][5] + x1[1];
        r1[2] = acc[si][6] + x1[2]; r1[3] = acc[si][7] + x1[3];
        *(f32x4*)(outp + e)     = r0;
        *(f32x4*)(outp + e + 4) = r1;
    }
}

// ---------------------------------------------------------------- 96->32 channel mix
template<int ACCUM>
__global__ __launch_bounds__(256)
void k_mix(const u16* __restrict__ G, const u16* __restrict__ H1,
           const u16* __restrict__ H2, const float* __restrict__ mw,
           const float* __restrict__ mb, float* __restrict__ OUT)
{
    __shared__ alignas(16) u16 Gs[4096], H1s[4096], H2s[4096];
    __shared__ float mwl[32 * 97];
    __shared__ float mbl[32];
    const int tid = threadIdx.x;
    const int b = blockIdx.x >> 7, xn = blockIdx.x & 127;
    size_t base = (size_t)b * 524288 + xn * 128;
    for (int p = 0; p < 2; ++p) {
        int chunk = p * 256 + tid, c = chunk >> 4, l8 = (chunk & 15) * 8;
        size_t src = base + (size_t)c * 16384 + l8;
        *(uint4*)&Gs[c * 128 + l8]  = *(const uint4*)(G + src);
        *(uint4*)&H1s[c * 128 + l8] = *(const uint4*)(H1 + src);
        *(uint4*)&H2s[c * 128 + l8] = *(const uint4*)(H2 + src);
    }
    for (int i = tid; i < 3072; i += 256) mwl[(i / 96) * 97 + (i % 96)] = mw[i];
    if (tid < 32) mbl[tid] = mb[tid];
    __syncthreads();
    const int og = (tid & 7) * 4, l0 = (tid >> 3) * 4;
    float acc[4][4];
    #pragma unroll
    for (int oi = 0; oi < 4; ++oi) {
        float bv = mbl[og + oi];
        acc[oi][0] = bv; acc[oi][1] = bv; acc[oi][2] = bv; acc[oi][3] = bv;
    }
    for (int c = 0; c < 32; ++c) {
        uint2 ga = *(const uint2*)&Gs[c * 128 + l0];
        uint2 h1 = *(const uint2*)&H1s[c * 128 + l0];
        uint2 h2 = *(const uint2*)&H2s[c * 128 + l0];
        float gv[4], v1[4], v2[4];
        gv[0] = __uint_as_float(ga.x << 16); gv[1] = __uint_as_float(ga.x & 0xffff0000u);
        gv[2] = __uint_as_float(ga.y << 16); gv[3] = __uint_as_float(ga.y & 0xffff0000u);
        v1[0] = __uint_as_float(h1.x << 16); v1[1] = __uint_as_float(h1.x & 0xffff0000u);
        v1[2] = __uint_as_float(h1.y << 16); v1[3] = __uint_as_float(h1.y & 0xffff0000u);
        v2[0] = __uint_as_float(h2.x << 16); v2[1] = __uint_as_float(h2.x & 0xffff0000u);
        v2[2] = __uint_as_float(h2.y << 16); v2[3] = __uint_as_float(h2.y & 0xffff0000u);
        #pragma unroll
        for (int oi = 0; oi < 4; ++oi) {
            int o = og + oi;
            float w0 = mwl[o * 97 + c], w1 = mwl[o * 97 + 32 + c], w2 = mwl[o * 97 + 64 + c];
            #pragma unroll
            for (int li = 0; li < 4; ++li)
                acc[oi][li] += gv[li] * w0 + v1[li] * w1 + v2[li] * w2;
        }
    }
    #pragma unroll
    for (int oi = 0; oi < 4; ++oi) {
        size_t e = ((size_t)(b * 32 + og + oi) * 128 + xn) * 128 + l0;
        f32x4 v; v[0] = acc[oi][0]; v[1] = acc[oi][1]; v[2] = acc[oi][2]; v[3] = acc[oi][3];
        if (ACCUM) { f32x4 old = *(const f32x4*)(OUT + e); v += old; }
        *(f32x4*)(OUT + e) = v;
    }
}

// ---------------------------------------------------------------- LayerNorm (2-stage, deterministic)
__global__ __launch_bounds__(256)
void k_lnsum(const float* __restrict__ OUT, const float* __restrict__ xin,
             float* __restrict__ partial)
{
    const int tid = threadIdx.x;
    const int b = blockIdx.x >> 7, chunk = blockIdx.x & 127;
    size_t base = (size_t)b * 524288 + (size_t)chunk * 4096;
    float s = 0.f, ss = 0.f;
    #pragma unroll
    for (int q = 0; q < 4; ++q) {
        size_t e = base + q * 1024 + tid * 4;
        f32x4 ov = *(const f32x4*)(OUT + e);
        f32x4 xv = *(const f32x4*)(xin + e);
        float y0 = ov[0] + xv[0];
        float y1 = ov[1] + xv[1];
        float y2 = ov[2] + xv[2];
        float y3 = ov[3] + xv[3];
        s += y0 + y1 + y2 + y3;
        ss += y0 * y0 + y1 * y1 + y2 * y2 + y3 * y3;
    }
    #pragma unroll
    for (int o = 32; o > 0; o >>= 1) {
        s  += __shfl_down(s,  o, 64);
        ss += __shfl_down(ss, o, 64);
    }
    __shared__ float sred[8];
    int w = tid >> 6;
    if ((tid & 63) == 0) { sred[w * 2] = s; sred[w * 2 + 1] = ss; }
    __syncthreads();
    if (tid == 0) {
        partial[blockIdx.x * 2]     = sred[0] + sred[2] + sred[4] + sred[6];
        partial[blockIdx.x * 2 + 1] = sred[1] + sred[3] + sred[5] + sred[7];
    }
}

__global__ __launch_bounds__(256)
void k_lnnorm(const float* __restrict__ OUT, const float* __restrict__ xin,
              const float* __restrict__ partial, const int* __restrict__ idxp,
              const float* __restrict__ lnw, const float* __restrict__ lnb,
              float* __restrict__ outx)
{
    const int tid = threadIdx.x;
    const int b = blockIdx.x >> 7, chunk = blockIdx.x & 127;
    float s = 0.f, ss = 0.f;
    if (tid < 128) {
        s  = partial[(b * 128 + tid) * 2];
        ss = partial[(b * 128 + tid) * 2 + 1];
    }
    #pragma unroll
    for (int o = 32; o > 0; o >>= 1) {
        s  += __shfl_down(s,  o, 64);
        ss += __shfl_down(ss, o, 64);
    }
    __shared__ float sred[4];
    __shared__ float mv[2];
    if ((tid & 63) == 0 && tid < 128) { sred[(tid >> 6) * 2] = s; sred[(tid >> 6) * 2 + 1] = ss; }
    __syncthreads();
    if (tid == 0) {
        float S = sred[0] + sred[2], SS = sred[1] + sred[3];
        float mean = S * (1.f / 524288.f);
        float var = SS * (1.f / 524288.f) - mean * mean;
        mv[0] = mean; mv[1] = rsqrtf(var + 1e-5f);
    }
    __syncthreads();
    const float mean = mv[0], rstd = mv[1];
    #pragma unroll
    for (int q = 0; q < 4; ++q) {
        int ib = chunk * 4096 + q * 1024 + tid * 4;   // in-batch flat index (4 consecutive)
        size_t e = (size_t)b * 524288 + ib;
        f32x4 ov = *(const f32x4*)(OUT + e);
        f32x4 xv = *(const f32x4*)(xin + e);
        int c = ib >> 14, xn = (ib >> 7) & 127, l = ib & 127;
        int ix = idxp[xn];
        size_t we = ((size_t)c * 128 + ix) * 128 + l;
        f32x4 wv = *(const f32x4*)(lnw + we);
        f32x4 bv = *(const f32x4*)(lnb + we);
        f32x4 r;
        #pragma unroll
        for (int j = 0; j < 4; ++j) {
            float y = ov[j] + xv[j];
            r[j] = (y - mean) * rstd * wv[j] + bv[j];
        }
        *(f32x4*)(outx + e) = r;
    }
}

// ---------------------------------------------------------------- launcher
extern "C" void kernel_launch(void* const* d_in, const int* in_sizes, int n_in,
                              void* d_out, int out_size, void* d_ws, size_t ws_size,
                              hipStream_t stream)
{
    (void)in_sizes; (void)n_in; (void)out_size; (void)ws_size;
    const float* x      = (const float*)d_in[0];
    const float* xskip  = (const float*)d_in[1];
    const float* A      = (const float*)d_in[2];
    const int*   idxp   = (const int*)d_in[3];
    const float* fw2p = (const float*)d_in[4];  const float* fb2p = (const float*)d_in[5];
    const float* fw3p = (const float*)d_in[6];  const float* fb3p = (const float*)d_in[7];
    const float* fw6p = (const float*)d_in[8];  const float* fb6p = (const float*)d_in[9];
    const float* fw7p = (const float*)d_in[10]; const float* fb7p = (const float*)d_in[11];
    const float* gw2p = (const float*)d_in[12]; const float* gb2p = (const float*)d_in[13];
    const float* gw3p = (const float*)d_in[14]; const float* gb3p = (const float*)d_in[15];
    const float* gw6p = (const float*)d_in[16]; const float* gb6p = (const float*)d_in[17];
    const float* gw7p = (const float*)d_in[18]; const float* gb7p = (const float*)d_in[19];
    const float* sw   = (const float*)d_in[20]; const float* sb   = (const float*)d_in[21];
    const float* mp1_gw = (const float*)d_in[22]; const float* mp1_gb = (const float*)d_in[23];
    const float* mp1_mw = (const float*)d_in[24]; const float* mp1_mb = (const float*)d_in[25];
    const float* mp2_gw = (const float*)d_in[26]; const float* mp2_gb = (const float*)d_in[27];
    const float* mp2_mw = (const float*)d_in[28]; const float* mp2_mb = (const float*)d_in[29];
    const float* lnw = (const float*)d_in[30]; const float* lnb = (const float*)d_in[31];

    char* wsb = (char*)d_ws;
    u16*   G   = (u16*)(wsb);                       // 16,777,216 B
    float* T1  = (float*)(wsb + 16777216);          // 33,554,432 B (XW)
    u16*   H1  = (u16*)(wsb + 50331648);            // 16,777,216 B
    u16*   H2  = (u16*)(wsb + 67108864);            // 16,777,216 B
    float* OUT = (float*)(wsb + 83886080);          // 33,554,432 B
    float* part= (float*)(wsb + 117440512);         // 16,384 B
    float* dd  = (float*)(wsb + 117456896);         // 2,048 B
    u16*   Wbf = (u16*)(wsb + 117460992);           // 33,554,432 B (bf16 weights, reused)
    float *dis1 = dd, *inv1 = dd + 128, *dis2 = dd + 256, *inv2 = dd + 384;

    float* out_x  = (float*)d_out;
    float* out_sk = out_x + 8388608;

    k_prep<<<1, 128, 0, stream>>>(A, dis1, inv1, dis2, inv2);
    k_incep<<<2048, 256, 0, stream>>>(x, fw2p, fw3p, fw6p, fw7p, fb2p, fb3p, fb6p, fb7p,
                                      gw2p, gw3p, gw6p, gw7p, gb2p, gb3p, gb6p, gb7p, G);
    k_skip<<<2048, 256, 0, stream>>>(G, xskip, sw, sb, out_sk);

    dim3 gg(32, 16);
    // mixprop 1 (A)
    k_wcvt<<<8192, 256, 0, stream>>>(mp1_gw, Wbf);
    k_gemm_bt<<<gg, 256, 0, stream>>>(G, Wbf, T1, 2048, 4096, 4096);
    k_gcn<0><<<8192, 256, 0, stream>>>(T1, G, A, dis1, inv1, mp1_gb, H1);
    k_wcvt<<<8192, 256, 0, stream>>>(mp1_gw + (size_t)16777216, Wbf);
    k_gemm_bt<<<gg, 256, 0, stream>>>(H1, Wbf, T1, 2048, 4096, 4096);
    k_gcn<0><<<8192, 256, 0, stream>>>(T1, G, A, dis1, inv1, mp1_gb + 4096, H2);
    k_mix<0><<<2048, 256, 0, stream>>>(G, H1, H2, mp1_mw, mp1_mb, OUT);
    // mixprop 2 (A^T)
    k_wcvt<<<8192, 256, 0, stream>>>(mp2_gw, Wbf);
    k_gemm_bt<<<gg, 256, 0, stream>>>(G, Wbf, T1, 2048, 4096, 4096);
    k_gcn<1><<<8192, 256, 0, stream>>>(T1, G, A, dis2, inv2, mp2_gb, H1);
    k_wcvt<<<8192, 256, 0, stream>>>(mp2_gw + (size_t)16777216, Wbf);
    k_gemm_bt<<<gg, 256, 0, stream>>>(H1, Wbf, T1, 2048, 4096, 4096);
    k_gcn<1><<<8192, 256, 0, stream>>>(T1, G, A, dis2, inv2, mp2_gb + 4096, H2);
    k_mix<1><<<2048, 256, 0, stream>>>(G, H1, H2, mp2_mw, mp2_mb, OUT);
    // layernorm (+ x residual) -> out
    k_lnsum<<<2048, 256, 0, stream>>>(OUT, x, part);
    k_lnnorm<<<2048, 256, 0, stream>>>(OUT, x, part, idxp, lnw, lnb, out_x);
}

// Round 4
// 844.963 us; speedup vs baseline: 1.2435x; 1.0510x over previous
//
#include <hip/hip_runtime.h>
#include <stdint.h>

typedef unsigned short u16;
typedef unsigned int   u32;
typedef __attribute__((ext_vector_type(4))) float f32x4;
typedef __attribute__((ext_vector_type(8))) short bf16x8;

__device__ __forceinline__ u16 f2bf(float f) {
    u32 i = __float_as_uint(f);
    u32 r = (i + 0x7fffu + ((i >> 16) & 1u)) >> 16;   // RNE
    return (u16)r;
}
__device__ __forceinline__ u32 cvt2bf(float a, float b) {
    u32 r;
    asm("v_cvt_pk_bf16_f32 %0, %1, %2" : "=v"(r) : "v"(a), "v"(b));
    return r;
}

#define GLOAD16(g, l) __builtin_amdgcn_global_load_lds( \
    (const __attribute__((address_space(1))) void*)(g), \
    (__attribute__((address_space(3))) void*)(l), 16, 0, 0)

// ---------------------------------------------------------------- prep: degrees
__global__ void k_prep(const float* __restrict__ A, float* dis1, float* inv1,
                       float* dis2, float* inv2)
{
    int r = threadIdx.x;
    if (r >= 128) return;
    int cc = 0, cr = 0;
    for (int j = 0; j < 128; ++j) {
        if (j == r) continue;
        if (A[(j << 7) + r] != 0.f) cc++;   // column count (mp1)
        if (A[(r << 7) + j] != 0.f) cr++;   // row count (mp2, A^T)
    }
    float d1 = 1.f + (float)cc, d2 = 1.f + (float)cr;
    dis1[r] = rsqrtf(d1); inv1[r] = 1.f / d1;
    dis2[r] = rsqrtf(d2); inv2[r] = 1.f / d2;
}

// ---------------------------------------------------------------- weight f32 -> bf16 (streaming)
__global__ __launch_bounds__(256)
void k_wcvt(const float* __restrict__ W, u16* __restrict__ Wb)
{
    size_t e = ((size_t)blockIdx.x * 256 + threadIdx.x) * 8;   // grid 8192 -> 16M elems
    f32x4 a = *(const f32x4*)(W + e);
    f32x4 b = *(const f32x4*)(W + e + 4);
    uint4 r;
    r.x = cvt2bf(a[0], a[1]); r.y = cvt2bf(a[2], a[3]);
    r.z = cvt2bf(b[0], b[1]); r.w = cvt2bf(b[2], b[3]);
    *(uint4*)(Wb + e) = r;
}

// ---------------------------------------------------------------- GEMM: C = A @ B^T (dual-problem, z-select)
// A: M x K bf16, B: N x K bf16, C: M x N f32. m97 structure, 128x128 tile, BK=32.
// blockIdx flattened + bijective XCD swizzle; blockIdx.z selects problem {0,1}.
__global__ __launch_bounds__(256, 2)
void k_gemm2(const u16* __restrict__ A0, const u16* __restrict__ A1,
             const u16* __restrict__ B0, const u16* __restrict__ B1,
             float* __restrict__ C0, float* __restrict__ C1,
             int M, int N, int K)
{
    __shared__ alignas(16) u16 As[128 * 32];
    __shared__ alignas(16) u16 Bs[128 * 32];
    const int tid  = threadIdx.x;
    const int lane = tid & 63;
    const int w    = tid >> 6;

    // flatten grid (x fast, then y, then z) and XCD-swizzle (nwg % 8 == 0, bijective)
    int bid = (blockIdx.z * gridDim.y + blockIdx.y) * gridDim.x + blockIdx.x;
    int nwg = gridDim.x * gridDim.y * gridDim.z;     // 512 or 1024
    int cpx = nwg >> 3;
    int swz = (bid & 7) * cpx + (bid >> 3);
    int z   = swz >> 9;                              // /512 (gridDim.x*y = 512)
    int rem = swz & 511;
    const int bm = (rem >> 5) * 128, bn = (rem & 31) * 128;
    const int wm = (w >> 1) * 64,    wn = (w & 1) * 64;

    const u16* A = z ? A1 : A0;
    const u16* B = z ? B1 : B0;
    float*     C = z ? C1 : C0;

    const int srow = tid >> 2, scol = (tid & 3) * 8;
    const u16* ag = A + (size_t)(bm + srow) * K + scol;
    const u16* bg = B + (size_t)(bn + srow) * K + scol;
    u16* asl = As + tid * 8;
    u16* bsl = Bs + tid * 8;
    const size_t rstep = (size_t)64 * K;

    f32x4 acc[4][4] = {};
    const int lr = lane & 15, lkb = (lane >> 4) * 8;

    for (int k0 = 0; k0 < K; k0 += 32) {
        GLOAD16(ag + k0,         asl);
        GLOAD16(ag + k0 + rstep, asl + 2048);
        GLOAD16(bg + k0,         bsl);
        GLOAD16(bg + k0 + rstep, bsl + 2048);
        __syncthreads();                     // drains vmcnt: tiles ready
        bf16x8 af[4], bfv[4];
        #pragma unroll
        for (int i = 0; i < 4; ++i) {
            af[i]  = *(const bf16x8*)(As + (wm + i * 16 + lr) * 32 + lkb);
            bfv[i] = *(const bf16x8*)(Bs + (wn + i * 16 + lr) * 32 + lkb);
        }
        #pragma unroll
        for (int i = 0; i < 4; ++i)
            #pragma unroll
            for (int j = 0; j < 4; ++j)
                acc[i][j] = __builtin_amdgcn_mfma_f32_16x16x32_bf16(af[i], bfv[j], acc[i][j], 0, 0, 0);
        __syncthreads();                     // protect LDS for next iter
    }

    const int orow = (lane >> 4) * 4, ocol = lane & 15;
    #pragma unroll
    for (int i = 0; i < 4; ++i) {
        #pragma unroll
        for (int j = 0; j < 4; ++j) {
            float* cp = C + (size_t)(bm + wm + i * 16 + orow) * N + (bn + wn + j * 16 + ocol);
            #pragma unroll
            for (int v = 0; v < 4; ++v)
                cp[(size_t)v * N] = acc[i][j][v];
        }
    }
}

// ---------------------------------------------------------------- GCN normalize + alpha residual
// Hout = bf16( 0.05*G + XW*invdeg[r] + (r<128: dis[r]*sum_j Aoff*dis[j]*XW[j]) + gb[o] )
template<int TR>
__global__ __launch_bounds__(256)
void k_gcn(const float* __restrict__ XW, const u16* __restrict__ G,
           const float* __restrict__ Af, const float* __restrict__ dis,
           const float* __restrict__ invdeg, const float* __restrict__ gbias,
           u16* __restrict__ Hout)
{
    int t4 = blockIdx.x * 256 + threadIdx.x;       // grid 8192 -> 2M threads, 4 elems each
    int r = t4 >> 10, og = (t4 & 1023) << 2;
    size_t e = ((size_t)r << 12) + og;
    f32x4 out = *(const f32x4*)(XW + e);
    if (r < 128) {
        float iv = invdeg[r];
        f32x4 s = {0.f, 0.f, 0.f, 0.f};
        for (int j = 0; j < 128; ++j) {
            float av = TR ? Af[(r << 7) + j] : Af[(j << 7) + r];
            float wv = ((av != 0.f) && (j != r)) ? dis[j] : 0.f;
            f32x4 xv = *(const f32x4*)(XW + ((size_t)j << 12) + og);
            #pragma unroll
            for (int q = 0; q < 4; ++q) s[q] = __fmaf_rn(wv, xv[q], s[q]);
        }
        float dr = dis[r];
        #pragma unroll
        for (int q = 0; q < 4; ++q) out[q] = __fmaf_rn(dr, s[q], out[q] * iv);
    }
    f32x4 gb4 = *(const f32x4*)(gbias + og);
    uint2 gv = *(const uint2*)(G + e);
    float g0 = __uint_as_float(gv.x << 16), g1 = __uint_as_float(gv.x & 0xffff0000u);
    float g2 = __uint_as_float(gv.y << 16), g3 = __uint_as_float(gv.y & 0xffff0000u);
    float y0 = __fmaf_rn(0.05f, g0, out[0] + gb4[0]);
    float y1 = __fmaf_rn(0.05f, g1, out[1] + gb4[1]);
    float y2 = __fmaf_rn(0.05f, g2, out[2] + gb4[2]);
    float y3 = __fmaf_rn(0.05f, g3, out[3] + gb4[3]);
    uint2 rr;
    rr.x = cvt2bf(y0, y1);
    rr.y = cvt2bf(y2, y3);
    *(uint2*)(Hout + e) = rr;
}

// ---------------------------------------------------------------- inception + gate (wave-balanced)
__device__ __forceinline__ constexpr int wbase_of(int k) {
    return k == 2 ? 0 : k == 3 ? 520 : k == 6 ? 1296 : 2840;
}
__device__ __forceinline__ constexpr int ob_of(int k) {
    return k == 2 ? 0 : k == 3 ? 8 : k == 6 ? 16 : 24;
}

// one (branch, 8-L-block) phase: 8 outputs per lane
template<int K_>
__device__ __forceinline__ void conv_phase(const float* __restrict__ xsb,   // xs + l0
                                           const float* __restrict__ wfp,   // wfl+base+oo*stride
                                           const float* __restrict__ wgp,
                                           float fb, float gb,
                                           u16* __restrict__ Gp)
{
    float accf[8], accg[8];
    #pragma unroll
    for (int i = 0; i < 8; ++i) { accf[i] = fb; accg[i] = gb; }
    for (int c = 0; c < 32; ++c) {
        float xw[24];                                  // covers L [l0-8, l0+16)
        const float* xr = xsb + c * 144;
        #pragma unroll
        for (int q = 0; q < 6; ++q) {
            f32x4 v = *(const f32x4*)(xr + q * 4);
            xw[q * 4 + 0] = v[0]; xw[q * 4 + 1] = v[1];
            xw[q * 4 + 2] = v[2]; xw[q * 4 + 3] = v[3];
        }
        float wfj[K_], wgj[K_];
        const float* wfc = wfp + c * K_;
        const float* wgc = wgp + c * K_;
        #pragma unroll
        for (int j = 0; j < K_; ++j) { wfj[j] = wfc[j]; wgj[j] = wgc[j]; }
        #pragma unroll
        for (int li = 0; li < 8; ++li) {
            #pragma unroll
            for (int j = 0; j < K_; ++j) {
                float xv = xw[li + 8 - (K_ - 1) + 2 * j];
                accf[li] = __fmaf_rn(xv, wfj[j], accf[li]);
                accg[li] = __fmaf_rn(xv, wgj[j], accg[li]);
            }
        }
    }
    u16 o8[8];
    #pragma unroll
    for (int i = 0; i < 8; ++i) {
        // overflow-safe fast tanh/sigmoid (inf -> saturates, no NaN)
        float e2 = __expf(2.f * accf[i]);
        float th = 1.f - __fdividef(2.f, e2 + 1.f);
        float sg = __fdividef(1.f, 1.f + __expf(-accg[i]));
        o8[i] = f2bf(th * sg);
    }
    uint4 u;
    u.x = o8[0] | ((u32)o8[1] << 16); u.y = o8[2] | ((u32)o8[3] << 16);
    u.z = o8[4] | ((u32)o8[5] << 16); u.w = o8[6] | ((u32)o8[7] << 16);
    *(uint4*)Gp = u;
}

// wave does branch KA on L[0,64) and branch KB on L[64,128): balanced 9 k-units each
template<int KA, int KB>
__device__ __forceinline__ void wave_pair(const float* __restrict__ xs,
                                          const float* __restrict__ wfl,
                                          const float* __restrict__ wgl,
                                          const float* __restrict__ fbl,
                                          const float* __restrict__ gbl,
                                          int oo, int lL, int b, int n,
                                          u16* __restrict__ G)
{
    {
        constexpr int BS = wbase_of(KA), ST = 32 * KA + 1, OB = ob_of(KA);
        const int o = OB + oo, l0 = lL * 8;
        conv_phase<KA>(xs + l0, wfl + BS + oo * ST, wgl + BS + oo * ST,
                       fbl[o], gbl[o],
                       G + (((size_t)(b * 32 + o) * 128 + n) * 128 + l0));
    }
    {
        constexpr int BS = wbase_of(KB), ST = 32 * KB + 1, OB = ob_of(KB);
        const int o = OB + oo, l0 = 64 + lL * 8;
        conv_phase<KB>(xs + l0, wfl + BS + oo * ST, wgl + BS + oo * ST,
                       fbl[o], gbl[o],
                       G + (((size_t)(b * 32 + o) * 128 + n) * 128 + l0));
    }
}

__global__ __launch_bounds__(256)
void k_incep(const float* __restrict__ x,
             const float* __restrict__ fw2p, const float* __restrict__ fw3p,
             const float* __restrict__ fw6p, const float* __restrict__ fw7p,
             const float* __restrict__ fb2p, const float* __restrict__ fb3p,
             const float* __restrict__ fb6p, const float* __restrict__ fb7p,
             const float* __restrict__ gw2p, const float* __restrict__ gw3p,
             const float* __restrict__ gw6p, const float* __restrict__ gw7p,
             const float* __restrict__ gb2p, const float* __restrict__ gb3p,
             const float* __restrict__ gb6p, const float* __restrict__ gb7p,
             u16* __restrict__ G)
{
    __shared__ alignas(16) float xs[32 * 144];       // +8 guard each side along L
    __shared__ float wfl[4640], wgl[4640];           // padded (32k+1) per oo
    __shared__ float fbl[32], gbl[32];
    const int tid = threadIdx.x;
    const int b = blockIdx.x >> 7, n = blockIdx.x & 127;

    for (int i = tid; i < 32 * 144; i += 256) xs[i] = 0.f;
    for (int g = tid; g < 4608; g += 256) {
        int rel, k, woff;
        const float *pf, *pg;
        if (g < 512)       { rel = g;        k = 2; woff = 0;    pf = fw2p; pg = gw2p; }
        else if (g < 1280) { rel = g - 512;  k = 3; woff = 520;  pf = fw3p; pg = gw3p; }
        else if (g < 2816) { rel = g - 1280; k = 6; woff = 1296; pf = fw6p; pg = gw6p; }
        else               { rel = g - 2816; k = 7; woff = 2840; pf = fw7p; pg = gw7p; }
        int ck = 32 * k;
        int oo = rel / ck, rem = rel % ck;
        int dst = woff + oo * (ck + 1) + rem;
        wfl[dst] = pf[rel];
        wgl[dst] = pg[rel];
    }
    if (tid < 32) {
        int br = tid >> 3, oo = tid & 7;
        const float* pf = br == 0 ? fb2p : br == 1 ? fb3p : br == 2 ? fb6p : fb7p;
        const float* pg = br == 0 ? gb2p : br == 1 ? gb3p : br == 2 ? gb6p : gb7p;
        fbl[tid] = pf[oo]; gbl[tid] = pg[oo];
    }
    __syncthreads();
    // stage x[b,:,n,:] into guarded f32 LDS
    const float* xb = x + (size_t)b * 524288 + n * 128;
    for (int p = 0; p < 4; ++p) {
        int chunk = p * 256 + tid;
        int c = chunk >> 5, l4 = (chunk & 31) * 4;
        *(f32x4*)&xs[c * 144 + 8 + l4] = *(const f32x4*)(xb + (size_t)c * 16384 + l4);
    }
    __syncthreads();

    const int w = tid >> 6, lane = tid & 63;
    const int oo = lane >> 3, lL = lane & 7;
    switch (w) {
        case 0:  wave_pair<2, 7>(xs, wfl, wgl, fbl, gbl, oo, lL, b, n, G); break;
        case 1:  wave_pair<7, 2>(xs, wfl, wgl, fbl, gbl, oo, lL, b, n, G); break;
        case 2:  wave_pair<3, 6>(xs, wfl, wgl, fbl, gbl, oo, lL, b, n, G); break;
        default: wave_pair<6, 3>(xs, wfl, wgl, fbl, gbl, oo, lL, b, n, G); break;
    }
}

// ---------------------------------------------------------------- skip projection
__global__ __launch_bounds__(256)
void k_skip(const u16* __restrict__ G, const float* __restrict__ xskip,
            const float* __restrict__ sw, const float* __restrict__ sb,
            float* __restrict__ outp)
{
    __shared__ alignas(16) u16 Gs[4096];
    __shared__ float swl[64 * 33];
    __shared__ float sbl[64];
    const int tid = threadIdx.x;
    const int b = blockIdx.x >> 7, n = blockIdx.x & 127;
    const u16* gb_ = G + (size_t)b * 524288 + n * 128;
    for (int p = 0; p < 2; ++p) {
        int chunk = p * 256 + tid, c = chunk >> 4, l8 = (chunk & 15) * 8;
        *(uint4*)&Gs[c * 128 + l8] = *(const uint4*)(gb_ + (size_t)c * 16384 + l8);
    }
    for (int i = tid; i < 2048; i += 256) swl[(i >> 5) * 33 + (i & 31)] = sw[i];
    if (tid < 64) sbl[tid] = sb[tid];
    __syncthreads();
    const int sg = (tid & 15) * 4, l0 = (tid >> 4) * 8;
    float acc[4][8];
    #pragma unroll
    for (int si = 0; si < 4; ++si) {
        float bv = sbl[sg + si];
        #pragma unroll
        for (int li = 0; li < 8; ++li) acc[si][li] = bv;
    }
    for (int c = 0; c < 32; ++c) {
        uint4 gv = *(const uint4*)&Gs[c * 128 + l0];
        float g[8];
        g[0] = __uint_as_float(gv.x << 16); g[1] = __uint_as_float(gv.x & 0xffff0000u);
        g[2] = __uint_as_float(gv.y << 16); g[3] = __uint_as_float(gv.y & 0xffff0000u);
        g[4] = __uint_as_float(gv.z << 16); g[5] = __uint_as_float(gv.z & 0xffff0000u);
        g[6] = __uint_as_float(gv.w << 16); g[7] = __uint_as_float(gv.w & 0xffff0000u);
        #pragma unroll
        for (int si = 0; si < 4; ++si) {
            float wv = swl[(sg + si) * 33 + c];
            #pragma unroll
            for (int li = 0; li < 8; ++li) acc[si][li] = __fmaf_rn(g[li], wv, acc[si][li]);
        }
    }
    #pragma unroll
    for (int si = 0; si < 4; ++si) {
        size_t e = ((size_t)(b * 64 + sg + si) * 128 + n) * 128 + l0;
        f32x4 x0 = *(const f32x4*)(xskip + e);
        f32x4 x1 = *(const f32x4*)(xskip + e + 4);
        f32x4 r0, r1;
        r0[0] = acc[si][0] + x0[0]; r0[1] = acc[si][1] + x0[1];
        r0[2] = acc[si][2] + x0[2]; r0[3] = acc[si][3] + x0[3];
        r1[0] = acc[si][4] + x1[0]; r1[1] = acc[si][5] + x1[1];
        r1[2] = acc[si][6] + x1[2]; r1[3] = acc[si][7] + x1[3];
        *(f32x4*)(outp + e)     = r0;
        *(f32x4*)(outp + e + 4) = r1;
    }
}

// ---------------------------------------------------------------- 96->32 channel mix
template<int ACCUM>
__global__ __launch_bounds__(256)
void k_mix(const u16* __restrict__ G, const u16* __restrict__ H1,
           const u16* __restrict__ H2, const float* __restrict__ mw,
           const float* __restrict__ mb, float* __restrict__ OUT)
{
    __shared__ alignas(16) u16 Gs[4096], H1s[4096], H2s[4096];
    __shared__ float mwl[32 * 97];
    __shared__ float mbl[32];
    const int tid = threadIdx.x;
    const int b = blockIdx.x >> 7, xn = blockIdx.x & 127;
    size_t base = (size_t)b * 524288 + xn * 128;
    for (int p = 0; p < 2; ++p) {
        int chunk = p * 256 + tid, c = chunk >> 4, l8 = (chunk & 15) * 8;
        size_t src = base + (size_t)c * 16384 + l8;
        *(uint4*)&Gs[c * 128 + l8]  = *(const uint4*)(G + src);
        *(uint4*)&H1s[c * 128 + l8] = *(const uint4*)(H1 + src);
        *(uint4*)&H2s[c * 128 + l8] = *(const uint4*)(H2 + src);
    }
    for (int i = tid; i < 3072; i += 256) mwl[(i / 96) * 97 + (i % 96)] = mw[i];
    if (tid < 32) mbl[tid] = mb[tid];
    __syncthreads();
    const int og = (tid & 7) * 4, l0 = (tid >> 3) * 4;
    float acc[4][4];
    #pragma unroll
    for (int oi = 0; oi < 4; ++oi) {
        float bv = mbl[og + oi];
        acc[oi][0] = bv; acc[oi][1] = bv; acc[oi][2] = bv; acc[oi][3] = bv;
    }
    for (int c = 0; c < 32; ++c) {
        uint2 ga = *(const uint2*)&Gs[c * 128 + l0];
        uint2 h1 = *(const uint2*)&H1s[c * 128 + l0];
        uint2 h2 = *(const uint2*)&H2s[c * 128 + l0];
        float gv[4], v1[4], v2[4];
        gv[0] = __uint_as_float(ga.x << 16); gv[1] = __uint_as_float(ga.x & 0xffff0000u);
        gv[2] = __uint_as_float(ga.y << 16); gv[3] = __uint_as_float(ga.y & 0xffff0000u);
        v1[0] = __uint_as_float(h1.x << 16); v1[1] = __uint_as_float(h1.x & 0xffff0000u);
        v1[2] = __uint_as_float(h1.y << 16); v1[3] = __uint_as_float(h1.y & 0xffff0000u);
        v2[0] = __uint_as_float(h2.x << 16); v2[1] = __uint_as_float(h2.x & 0xffff0000u);
        v2[2] = __uint_as_float(h2.y << 16); v2[3] = __uint_as_float(h2.y & 0xffff0000u);
        #pragma unroll
        for (int oi = 0; oi < 4; ++oi) {
            int o = og + oi;
            float w0 = mwl[o * 97 + c], w1 = mwl[o * 97 + 32 + c], w2 = mwl[o * 97 + 64 + c];
            #pragma unroll
            for (int li = 0; li < 4; ++li)
                acc[oi][li] += gv[li] * w0 + v1[li] * w1 + v2[li] * w2;
        }
    }
    #pragma unroll
    for (int oi = 0; oi < 4; ++oi) {
        size_t e = ((size_t)(b * 32 + og + oi) * 128 + xn) * 128 + l0;
        f32x4 v; v[0] = acc[oi][0]; v[1] = acc[oi][1]; v[2] = acc[oi][2]; v[3] = acc[oi][3];
        if (ACCUM) { f32x4 old = *(const f32x4*)(OUT + e); v += old; }
        *(f32x4*)(OUT + e) = v;
    }
}

// ---------------------------------------------------------------- LayerNorm (2-stage, deterministic)
__global__ __launch_bounds__(256)
void k_lnsum(const float* __restrict__ OUT, const float* __restrict__ xin,
             float* __restrict__ partial)
{
    const int tid = threadIdx.x;
    const int b = blockIdx.x >> 7, chunk = blockIdx.x & 127;
    size_t base = (size_t)b * 524288 + (size_t)chunk * 4096;
    float s = 0.f, ss = 0.f;
    #pragma unroll
    for (int q = 0; q < 4; ++q) {
        size_t e = base + q * 1024 + tid * 4;
        f32x4 ov = *(const f32x4*)(OUT + e);
        f32x4 xv = *(const f32x4*)(xin + e);
        float y0 = ov[0] + xv[0];
        float y1 = ov[1] + xv[1];
        float y2 = ov[2] + xv[2];
        float y3 = ov[3] + xv[3];
        s += y0 + y1 + y2 + y3;
        ss += y0 * y0 + y1 * y1 + y2 * y2 + y3 * y3;
    }
    #pragma unroll
    for (int o = 32; o > 0; o >>= 1) {
        s  += __shfl_down(s,  o, 64);
        ss += __shfl_down(ss, o, 64);
    }
    __shared__ float sred[8];
    int w = tid >> 6;
    if ((tid & 63) == 0) { sred[w * 2] = s; sred[w * 2 + 1] = ss; }
    __syncthreads();
    if (tid == 0) {
        partial[blockIdx.x * 2]     = sred[0] + sred[2] + sred[4] + sred[6];
        partial[blockIdx.x * 2 + 1] = sred[1] + sred[3] + sred[5] + sred[7];
    }
}

__global__ __launch_bounds__(256)
void k_lnnorm(const float* __restrict__ OUT, const float* __restrict__ xin,
              const float* __restrict__ partial, const int* __restrict__ idxp,
              const float* __restrict__ lnw, const float* __restrict__ lnb,
              float* __restrict__ outx)
{
    const int tid = threadIdx.x;
    const int b = blockIdx.x >> 7, chunk = blockIdx.x & 127;
    float s = 0.f, ss = 0.f;
    if (tid < 128) {
        s  = partial[(b * 128 + tid) * 2];
        ss = partial[(b * 128 + tid) * 2 + 1];
    }
    #pragma unroll
    for (int o = 32; o > 0; o >>= 1) {
        s  += __shfl_down(s,  o, 64);
        ss += __shfl_down(ss, o, 64);
    }
    __shared__ float sred[4];
    __shared__ float mv[2];
    if ((tid & 63) == 0 && tid < 128) { sred[(tid >> 6) * 2] = s; sred[(tid >> 6) * 2 + 1] = ss; }
    __syncthreads();
    if (tid == 0) {
        float S = sred[0] + sred[2], SS = sred[1] + sred[3];
        float mean = S * (1.f / 524288.f);
        float var = SS * (1.f / 524288.f) - mean * mean;
        mv[0] = mean; mv[1] = rsqrtf(var + 1e-5f);
    }
    __syncthreads();
    const float mean = mv[0], rstd = mv[1];
    #pragma unroll
    for (int q = 0; q < 4; ++q) {
        int ib = chunk * 4096 + q * 1024 + tid * 4;   // in-batch flat index (4 consecutive)
        size_t e = (size_t)b * 524288 + ib;
        f32x4 ov = *(const f32x4*)(OUT + e);
        f32x4 xv = *(const f32x4*)(xin + e);
        int c = ib >> 14, xn = (ib >> 7) & 127, l = ib & 127;
        int ix = idxp[xn];
        size_t we = ((size_t)c * 128 + ix) * 128 + l;
        f32x4 wv = *(const f32x4*)(lnw + we);
        f32x4 bv = *(const f32x4*)(lnb + we);
        f32x4 r;
        #pragma unroll
        for (int j = 0; j < 4; ++j) {
            float y = ov[j] + xv[j];
            r[j] = (y - mean) * rstd * wv[j] + bv[j];
        }
        *(f32x4*)(outx + e) = r;
    }
}

// ---------------------------------------------------------------- launcher
extern "C" void kernel_launch(void* const* d_in, const int* in_sizes, int n_in,
                              void* d_out, int out_size, void* d_ws, size_t ws_size,
                              hipStream_t stream)
{
    (void)in_sizes; (void)n_in; (void)out_size;
    const float* x      = (const float*)d_in[0];
    const float* xskip  = (const float*)d_in[1];
    const float* A      = (const float*)d_in[2];
    const int*   idxp   = (const int*)d_in[3];
    const float* fw2p = (const float*)d_in[4];  const float* fb2p = (const float*)d_in[5];
    const float* fw3p = (const float*)d_in[6];  const float* fb3p = (const float*)d_in[7];
    const float* fw6p = (const float*)d_in[8];  const float* fb6p = (const float*)d_in[9];
    const float* fw7p = (const float*)d_in[10]; const float* fb7p = (const float*)d_in[11];
    const float* gw2p = (const float*)d_in[12]; const float* gb2p = (const float*)d_in[13];
    const float* gw3p = (const float*)d_in[14]; const float* gb3p = (const float*)d_in[15];
    const float* gw6p = (const float*)d_in[16]; const float* gb6p = (const float*)d_in[17];
    const float* gw7p = (const float*)d_in[18]; const float* gb7p = (const float*)d_in[19];
    const float* sw   = (const float*)d_in[20]; const float* sb   = (const float*)d_in[21];
    const float* mp1_gw = (const float*)d_in[22]; const float* mp1_gb = (const float*)d_in[23];
    const float* mp1_mw = (const float*)d_in[24]; const float* mp1_mb = (const float*)d_in[25];
    const float* mp2_gw = (const float*)d_in[26]; const float* mp2_gb = (const float*)d_in[27];
    const float* mp2_mw = (const float*)d_in[28]; const float* mp2_mb = (const float*)d_in[29];
    const float* lnw = (const float*)d_in[30]; const float* lnb = (const float*)d_in[31];

    char* wsb = (char*)d_ws;
    float* out_x  = (float*)d_out;
    float* out_sk = out_x + 8388608;

    const size_t MB16 = 16777216, MB33 = 33554432;
    const size_t need_merged = 5 * MB16 + 4 * MB33 + 16384 + 2048;   // ~218 MB

    if (ws_size >= need_merged) {
        // ---------------- merged path: mp1 & mp2 GEMMs fused per hop (grid.z=2)
        u16*   G   = (u16*)(wsb);
        u16*   H1  = (u16*)(wsb + MB16);
        u16*   H1b = (u16*)(wsb + 2 * MB16);
        u16*   H2  = (u16*)(wsb + 3 * MB16);
        u16*   H2b = (u16*)(wsb + 4 * MB16);
        float* Ta  = (float*)(wsb + 5 * MB16);
        float* Tb  = (float*)(wsb + 5 * MB16 + MB33);
        u16*   Wb0 = (u16*)(wsb + 5 * MB16 + 2 * MB33);
        u16*   Wb1 = (u16*)(wsb + 5 * MB16 + 3 * MB33);
        float* OUT = (float*)Wb0;                        // reuse after last GEMM
        float* part= (float*)(wsb + 5 * MB16 + 4 * MB33);
        float* dd  = (float*)(wsb + 5 * MB16 + 4 * MB33 + 16384);
        float *dis1 = dd, *inv1 = dd + 128, *dis2 = dd + 256, *inv2 = dd + 384;

        k_prep<<<1, 128, 0, stream>>>(A, dis1, inv1, dis2, inv2);
        k_incep<<<2048, 256, 0, stream>>>(x, fw2p, fw3p, fw6p, fw7p, fb2p, fb3p, fb6p, fb7p,
                                          gw2p, gw3p, gw6p, gw7p, gb2p, gb3p, gb6p, gb7p, G);
        k_skip<<<2048, 256, 0, stream>>>(G, xskip, sw, sb, out_sk);

        dim3 gg2(32, 16, 2);
        // hop 1 (both mixprops)
        k_wcvt<<<8192, 256, 0, stream>>>(mp1_gw, Wb0);
        k_wcvt<<<8192, 256, 0, stream>>>(mp2_gw, Wb1);
        k_gemm2<<<gg2, 256, 0, stream>>>(G, G, Wb0, Wb1, Ta, Tb, 2048, 4096, 4096);
        k_gcn<0><<<8192, 256, 0, stream>>>(Ta, G, A, dis1, inv1, mp1_gb, H1);
        k_gcn<1><<<8192, 256, 0, stream>>>(Tb, G, A, dis2, inv2, mp2_gb, H1b);
        // hop 2 (both mixprops)
        k_wcvt<<<8192, 256, 0, stream>>>(mp1_gw + MB16, Wb0);   // MB16 f32 elems = 16M
        k_wcvt<<<8192, 256, 0, stream>>>(mp2_gw + MB16, Wb1);
        k_gemm2<<<gg2, 256, 0, stream>>>(H1, H1b, Wb0, Wb1, Ta, Tb, 2048, 4096, 4096);
        k_gcn<0><<<8192, 256, 0, stream>>>(Ta, G, A, dis1, inv1, mp1_gb + 4096, H2);
        k_gcn<1><<<8192, 256, 0, stream>>>(Tb, G, A, dis2, inv2, mp2_gb + 4096, H2b);
        // channel mix + LN
        k_mix<0><<<2048, 256, 0, stream>>>(G, H1, H2, mp1_mw, mp1_mb, OUT);
        k_mix<1><<<2048, 256, 0, stream>>>(G, H1b, H2b, mp2_mw, mp2_mb, OUT);
        k_lnsum<<<2048, 256, 0, stream>>>(OUT, x, part);
        k_lnnorm<<<2048, 256, 0, stream>>>(OUT, x, part, idxp, lnw, lnb, out_x);
    } else {
        // ---------------- fallback: sequential (R3 layout, ~151 MB)
        u16*   G   = (u16*)(wsb);
        float* T1  = (float*)(wsb + 16777216);
        u16*   H1  = (u16*)(wsb + 50331648);
        u16*   H2  = (u16*)(wsb + 67108864);
        float* OUT = (float*)(wsb + 83886080);
        float* part= (float*)(wsb + 117440512);
        float* dd  = (float*)(wsb + 117456896);
        u16*   Wbf = (u16*)(wsb + 117460992);
        float *dis1 = dd, *inv1 = dd + 128, *dis2 = dd + 256, *inv2 = dd + 384;

        k_prep<<<1, 128, 0, stream>>>(A, dis1, inv1, dis2, inv2);
        k_incep<<<2048, 256, 0, stream>>>(x, fw2p, fw3p, fw6p, fw7p, fb2p, fb3p, fb6p, fb7p,
                                          gw2p, gw3p, gw6p, gw7p, gb2p, gb3p, gb6p, gb7p, G);
        k_skip<<<2048, 256, 0, stream>>>(G, xskip, sw, sb, out_sk);

        dim3 gg(32, 16, 1);
        k_wcvt<<<8192, 256, 0, stream>>>(mp1_gw, Wbf);
        k_gemm2<<<gg, 256, 0, stream>>>(G, G, Wbf, Wbf, T1, T1, 2048, 4096, 4096);
        k_gcn<0><<<8192, 256, 0, stream>>>(T1, G, A, dis1, inv1, mp1_gb, H1);
        k_wcvt<<<8192, 256, 0, stream>>>(mp1_gw + 16777216, Wbf);
        k_gemm2<<<gg, 256, 0, stream>>>(H1, H1, Wbf, Wbf, T1, T1, 2048, 4096, 4096);
        k_gcn<0><<<8192, 256, 0, stream>>>(T1, G, A, dis1, inv1, mp1_gb + 4096, H2);
        k_mix<0><<<2048, 256, 0, stream>>>(G, H1, H2, mp1_mw, mp1_mb, OUT);
        k_wcvt<<<8192, 256, 0, stream>>>(mp2_gw, Wbf);
        k_gemm2<<<gg, 256, 0, stream>>>(G, G, Wbf, Wbf, T1, T1, 2048, 4096, 4096);
        k_gcn<1><<<8192, 256, 0, stream>>>(T1, G, A, dis2, inv2, mp2_gb, H1);
        k_wcvt<<<8192, 256, 0, stream>>>(mp2_gw + 16777216, Wbf);
        k_gemm2<<<gg, 256, 0, stream>>>(H1, H1, Wbf, Wbf, T1, T1, 2048, 4096, 4096);
        k_gcn<1><<<8192, 256, 0, stream>>>(T1, G, A, dis2, inv2, mp2_gb + 4096, H2);
        k_mix<1><<<2048, 256, 0, stream>>>(G, H1, H2, mp2_mw, mp2_mb, OUT);
        k_lnsum<<<2048, 256, 0, stream>>>(OUT, x, part);
        k_lnnorm<<<2048, 256, 0, stream>>>(OUT, x, part, idxp, lnw, lnb, out_x);
    }
}

// Round 5
// 738.561 us; speedup vs baseline: 1.4226x; 1.1441x over previous
//
#include <hip/hip_runtime.h>
#include <stdint.h>

typedef unsigned short u16;
typedef unsigned int   u32;
typedef __attribute__((ext_vector_type(4))) float f32x4;
typedef __attribute__((ext_vector_type(8))) short bf16x8;

__device__ __forceinline__ u16 f2bf(float f) {
    u32 i = __float_as_uint(f);
    u32 r = (i + 0x7fffu + ((i >> 16) & 1u)) >> 16;   // RNE
    return (u16)r;
}
__device__ __forceinline__ float bf2f(u16 u) {
    return __uint_as_float(((u32)u) << 16);
}
__device__ __forceinline__ u32 cvt2bf(float a, float b) {
    u32 r;
    asm("v_cvt_pk_bf16_f32 %0, %1, %2" : "=v"(r) : "v"(a), "v"(b));
    return r;
}

#define GLOAD16(g, l) __builtin_amdgcn_global_load_lds( \
    (const __attribute__((address_space(1))) void*)(g), \
    (__attribute__((address_space(3))) void*)(l), 16, 0, 0)

// ---------------------------------------------------------------- prep: degrees
__global__ void k_prep(const float* __restrict__ A, float* dis1, float* inv1,
                       float* dis2, float* inv2)
{
    int r = threadIdx.x;
    if (r >= 128) return;
    int cc = 0, cr = 0;
    for (int j = 0; j < 128; ++j) {
        if (j == r) continue;
        if (A[(j << 7) + r] != 0.f) cc++;   // column count (mp1)
        if (A[(r << 7) + j] != 0.f) cr++;   // row count (mp2, A^T)
    }
    float d1 = 1.f + (float)cc, d2 = 1.f + (float)cr;
    dis1[r] = rsqrtf(d1); inv1[r] = 1.f / d1;
    dis2[r] = rsqrtf(d2); inv2[r] = 1.f / d2;
}

// ---------------------------------------------------------------- weight f32 -> bf16 (both mixprops, one hop)
__global__ __launch_bounds__(256)
void k_wcvt2(const float* __restrict__ W0, const float* __restrict__ W1,
             u16* __restrict__ Wb0, u16* __restrict__ Wb1)
{
    int half = blockIdx.x >> 13;                      // grid 16384: 8192 per matrix
    const float* W = half ? W1 : W0;
    u16* Wb = half ? Wb1 : Wb0;
    size_t e = ((size_t)(blockIdx.x & 8191) * 256 + threadIdx.x) * 8;
    f32x4 a = *(const f32x4*)(W + e);
    f32x4 b = *(const f32x4*)(W + e + 4);
    uint4 r;
    r.x = cvt2bf(a[0], a[1]); r.y = cvt2bf(a[2], a[3]);
    r.z = cvt2bf(b[0], b[1]); r.w = cvt2bf(b[2], b[3]);
    *(uint4*)(Wb + e) = r;
}

// ---------------------------------------------------------------- GEMM + fused GCN-self epilogue
// Dual-problem (z from swizzle), A: 2048 x 4096 bf16, B: 4096 x 4096 bf16.
// Epilogue: H = bf16(XW + gb[o] + 0.05*G[r,o])  (valid for rows r>=128: deg=1;
// rows r<128 are overwritten by k_gcnfix). bm==0 blocks also dump the raw f32
// XW tile (rows 0..127) to XW0 for the graph-propagation fixup.
__global__ __launch_bounds__(256, 2)
void k_gemm2g(const u16* __restrict__ A0, const u16* __restrict__ A1,
              const u16* __restrict__ B0, const u16* __restrict__ B1,
              const u16* __restrict__ Gres,
              const float* __restrict__ gb0, const float* __restrict__ gb1,
              u16* __restrict__ Ha, u16* __restrict__ Hb,
              float* __restrict__ XW0a, float* __restrict__ XW0b)
{
    __shared__ alignas(16) u16 As[128 * 32];
    __shared__ alignas(16) u16 Bs[128 * 32];
    const int K = 4096;
    const int tid  = threadIdx.x;
    const int lane = tid & 63;
    const int w    = tid >> 6;

    // flatten grid (1024 WGs) + bijective XCD swizzle
    int bid = (blockIdx.z * gridDim.y + blockIdx.y) * gridDim.x + blockIdx.x;
    int swz = (bid & 7) * 128 + (bid >> 3);
    int z   = swz >> 9;
    int rem = swz & 511;
    const int bm = (rem >> 5) * 128, bn = (rem & 31) * 128;
    const int wm = (w >> 1) * 64,    wn = (w & 1) * 64;

    const u16* A = z ? A1 : A0;
    const u16* B = z ? B1 : B0;

    const int srow = tid >> 2, scol = (tid & 3) * 8;
    const u16* ag = A + (size_t)(bm + srow) * K + scol;
    const u16* bg = B + (size_t)(bn + srow) * K + scol;
    u16* asl = As + tid * 8;
    u16* bsl = Bs + tid * 8;
    const size_t rstep = (size_t)64 * K;

    f32x4 acc[4][4] = {};
    const int lr = lane & 15, lkb = (lane >> 4) * 8;

    for (int k0 = 0; k0 < K; k0 += 32) {
        GLOAD16(ag + k0,         asl);
        GLOAD16(ag + k0 + rstep, asl + 2048);
        GLOAD16(bg + k0,         bsl);
        GLOAD16(bg + k0 + rstep, bsl + 2048);
        __syncthreads();
        bf16x8 af[4], bfv[4];
        #pragma unroll
        for (int i = 0; i < 4; ++i) {
            af[i]  = *(const bf16x8*)(As + (wm + i * 16 + lr) * 32 + lkb);
            bfv[i] = *(const bf16x8*)(Bs + (wn + i * 16 + lr) * 32 + lkb);
        }
        #pragma unroll
        for (int i = 0; i < 4; ++i)
            #pragma unroll
            for (int j = 0; j < 4; ++j)
                acc[i][j] = __builtin_amdgcn_mfma_f32_16x16x32_bf16(af[i], bfv[j], acc[i][j], 0, 0, 0);
        __syncthreads();
    }

    const int orow = (lane >> 4) * 4, ocol = lane & 15;
    const float* gbv = z ? gb1 : gb0;
    u16* H = z ? Hb : Ha;

    #pragma unroll
    for (int j = 0; j < 4; ++j) {
        const int o = bn + wn + j * 16 + ocol;
        const float gbo = gbv[o];
        #pragma unroll
        for (int i = 0; i < 4; ++i) {
            const int rbase = bm + wm + i * 16 + orow;
            #pragma unroll
            for (int v = 0; v < 4; ++v) {
                const size_t e = (size_t)(rbase + v) * 4096 + o;
                float g = bf2f(Gres[e]);
                H[e] = f2bf(__fmaf_rn(0.05f, g, acc[i][j][v] + gbo));
            }
        }
    }
    if (bm == 0) {
        float* XW0 = z ? XW0b : XW0a;
        #pragma unroll
        for (int i = 0; i < 4; ++i) {
            #pragma unroll
            for (int j = 0; j < 4; ++j) {
                float* cp = XW0 + (size_t)(wm + i * 16 + orow) * 4096 + (bn + wn + j * 16 + ocol);
                #pragma unroll
                for (int v = 0; v < 4; ++v)
                    cp[(size_t)v * 4096] = acc[i][j][v];
            }
        }
    }
}

// ---------------------------------------------------------------- GCN fixup rows < 128 (both problems)
// H[r,o] = bf16(0.05*G + inv[r]*XW0[r,o] + dis[r]*sum_j wv[j]*XW0[j,o] + gb[o])
__global__ __launch_bounds__(256)
void k_gcnfix(const float* __restrict__ XW0a, const float* __restrict__ XW0b,
              const u16* __restrict__ G, const float* __restrict__ Af,
              const float* __restrict__ dis1, const float* __restrict__ inv1,
              const float* __restrict__ dis2, const float* __restrict__ inv2,
              const float* __restrict__ gb0, const float* __restrict__ gb1,
              u16* __restrict__ Ha, u16* __restrict__ Hb)
{
    const int prob = blockIdx.x >> 9;          // 0: mp1 (A), 1: mp2 (A^T)
    const int rem  = blockIdx.x & 511;
    const int t4 = rem * 256 + threadIdx.x;
    const int r = t4 >> 10, og = (t4 & 1023) << 2;
    const float* XW0 = prob ? XW0b : XW0a;
    const float* dis = prob ? dis2 : dis1;
    const float* inv = prob ? inv2 : inv1;
    const float* gb  = prob ? gb1  : gb0;
    u16* H = prob ? Hb : Ha;

    const size_t e = ((size_t)r << 12) + og;
    f32x4 xw = *(const f32x4*)(XW0 + e);
    f32x4 s = {0.f, 0.f, 0.f, 0.f};
    for (int j = 0; j < 128; ++j) {
        float av = prob ? Af[(r << 7) + j] : Af[(j << 7) + r];
        float wv = ((av != 0.f) && (j != r)) ? dis[j] : 0.f;
        f32x4 xv = *(const f32x4*)(XW0 + ((size_t)j << 12) + og);
        #pragma unroll
        for (int q = 0; q < 4; ++q) s[q] = __fmaf_rn(wv, xv[q], s[q]);
    }
    const float iv = inv[r], dr = dis[r];
    f32x4 gb4 = *(const f32x4*)(gb + og);
    uint2 gv = *(const uint2*)(G + e);
    float g0 = __uint_as_float(gv.x << 16), g1 = __uint_as_float(gv.x & 0xffff0000u);
    float g2 = __uint_as_float(gv.y << 16), g3 = __uint_as_float(gv.y & 0xffff0000u);
    float y0 = __fmaf_rn(0.05f, g0, __fmaf_rn(dr, s[0], xw[0] * iv) + gb4[0]);
    float y1 = __fmaf_rn(0.05f, g1, __fmaf_rn(dr, s[1], xw[1] * iv) + gb4[1]);
    float y2 = __fmaf_rn(0.05f, g2, __fmaf_rn(dr, s[2], xw[2] * iv) + gb4[2]);
    float y3 = __fmaf_rn(0.05f, g3, __fmaf_rn(dr, s[3], xw[3] * iv) + gb4[3]);
    uint2 rr;
    rr.x = cvt2bf(y0, y1);
    rr.y = cvt2bf(y2, y3);
    *(uint2*)(H + e) = rr;
}

// ---------------------------------------------------------------- inception + gate (wave-balanced)
__device__ __forceinline__ constexpr int wbase_of(int k) {
    return k == 2 ? 0 : k == 3 ? 520 : k == 6 ? 1296 : 2840;
}
__device__ __forceinline__ constexpr int ob_of(int k) {
    return k == 2 ? 0 : k == 3 ? 8 : k == 6 ? 16 : 24;
}

template<int K_>
__device__ __forceinline__ void conv_phase(const float* __restrict__ xsb,
                                           const float* __restrict__ wfp,
                                           const float* __restrict__ wgp,
                                           float fb, float gb,
                                           u16* __restrict__ Gp)
{
    float accf[8], accg[8];
    #pragma unroll
    for (int i = 0; i < 8; ++i) { accf[i] = fb; accg[i] = gb; }
    for (int c = 0; c < 32; ++c) {
        float xw[24];
        const float* xr = xsb + c * 144;
        #pragma unroll
        for (int q = 0; q < 6; ++q) {
            f32x4 v = *(const f32x4*)(xr + q * 4);
            xw[q * 4 + 0] = v[0]; xw[q * 4 + 1] = v[1];
            xw[q * 4 + 2] = v[2]; xw[q * 4 + 3] = v[3];
        }
        float wfj[K_], wgj[K_];
        const float* wfc = wfp + c * K_;
        const float* wgc = wgp + c * K_;
        #pragma unroll
        for (int j = 0; j < K_; ++j) { wfj[j] = wfc[j]; wgj[j] = wgc[j]; }
        #pragma unroll
        for (int li = 0; li < 8; ++li) {
            #pragma unroll
            for (int j = 0; j < K_; ++j) {
                float xv = xw[li + 8 - (K_ - 1) + 2 * j];
                accf[li] = __fmaf_rn(xv, wfj[j], accf[li]);
                accg[li] = __fmaf_rn(xv, wgj[j], accg[li]);
            }
        }
    }
    u16 o8[8];
    #pragma unroll
    for (int i = 0; i < 8; ++i) {
        float e2 = __expf(2.f * accf[i]);
        float th = 1.f - __fdividef(2.f, e2 + 1.f);
        float sg = __fdividef(1.f, 1.f + __expf(-accg[i]));
        o8[i] = f2bf(th * sg);
    }
    uint4 u;
    u.x = o8[0] | ((u32)o8[1] << 16); u.y = o8[2] | ((u32)o8[3] << 16);
    u.z = o8[4] | ((u32)o8[5] << 16); u.w = o8[6] | ((u32)o8[7] << 16);
    *(uint4*)Gp = u;
}

template<int KA, int KB>
__device__ __forceinline__ void wave_pair(const float* __restrict__ xs,
                                          const float* __restrict__ wfl,
                                          const float* __restrict__ wgl,
                                          const float* __restrict__ fbl,
                                          const float* __restrict__ gbl,
                                          int oo, int lL, int b, int n,
                                          u16* __restrict__ G)
{
    {
        constexpr int BS = wbase_of(KA), ST = 32 * KA + 1, OB = ob_of(KA);
        const int o = OB + oo, l0 = lL * 8;
        conv_phase<KA>(xs + l0, wfl + BS + oo * ST, wgl + BS + oo * ST,
                       fbl[o], gbl[o],
                       G + (((size_t)(b * 32 + o) * 128 + n) * 128 + l0));
    }
    {
        constexpr int BS = wbase_of(KB), ST = 32 * KB + 1, OB = ob_of(KB);
        const int o = OB + oo, l0 = 64 + lL * 8;
        conv_phase<KB>(xs + l0, wfl + BS + oo * ST, wgl + BS + oo * ST,
                       fbl[o], gbl[o],
                       G + (((size_t)(b * 32 + o) * 128 + n) * 128 + l0));
    }
}

__global__ __launch_bounds__(256)
void k_incep(const float* __restrict__ x,
             const float* __restrict__ fw2p, const float* __restrict__ fw3p,
             const float* __restrict__ fw6p, const float* __restrict__ fw7p,
             const float* __restrict__ fb2p, const float* __restrict__ fb3p,
             const float* __restrict__ fb6p, const float* __restrict__ fb7p,
             const float* __restrict__ gw2p, const float* __restrict__ gw3p,
             const float* __restrict__ gw6p, const float* __restrict__ gw7p,
             const float* __restrict__ gb2p, const float* __restrict__ gb3p,
             const float* __restrict__ gb6p, const float* __restrict__ gb7p,
             u16* __restrict__ G)
{
    __shared__ alignas(16) float xs[32 * 144];
    __shared__ float wfl[4640], wgl[4640];
    __shared__ float fbl[32], gbl[32];
    const int tid = threadIdx.x;
    const int b = blockIdx.x >> 7, n = blockIdx.x & 127;

    for (int i = tid; i < 32 * 144; i += 256) xs[i] = 0.f;
    for (int g = tid; g < 4608; g += 256) {
        int rel, k, woff;
        const float *pf, *pg;
        if (g < 512)       { rel = g;        k = 2; woff = 0;    pf = fw2p; pg = gw2p; }
        else if (g < 1280) { rel = g - 512;  k = 3; woff = 520;  pf = fw3p; pg = gw3p; }
        else if (g < 2816) { rel = g - 1280; k = 6; woff = 1296; pf = fw6p; pg = gw6p; }
        else               { rel = g - 2816; k = 7; woff = 2840; pf = fw7p; pg = gw7p; }
        int ck = 32 * k;
        int oo = rel / ck, rem = rel % ck;
        int dst = woff + oo * (ck + 1) + rem;
        wfl[dst] = pf[rel];
        wgl[dst] = pg[rel];
    }
    if (tid < 32) {
        int br = tid >> 3, oo = tid & 7;
        const float* pf = br == 0 ? fb2p : br == 1 ? fb3p : br == 2 ? fb6p : fb7p;
        const float* pg = br == 0 ? gb2p : br == 1 ? gb3p : br == 2 ? gb6p : gb7p;
        fbl[tid] = pf[oo]; gbl[tid] = pg[oo];
    }
    __syncthreads();
    const float* xb = x + (size_t)b * 524288 + n * 128;
    for (int p = 0; p < 4; ++p) {
        int chunk = p * 256 + tid;
        int c = chunk >> 5, l4 = (chunk & 31) * 4;
        *(f32x4*)&xs[c * 144 + 8 + l4] = *(const f32x4*)(xb + (size_t)c * 16384 + l4);
    }
    __syncthreads();

    const int w = tid >> 6, lane = tid & 63;
    const int oo = lane >> 3, lL = lane & 7;
    switch (w) {
        case 0:  wave_pair<2, 7>(xs, wfl, wgl, fbl, gbl, oo, lL, b, n, G); break;
        case 1:  wave_pair<7, 2>(xs, wfl, wgl, fbl, gbl, oo, lL, b, n, G); break;
        case 2:  wave_pair<3, 6>(xs, wfl, wgl, fbl, gbl, oo, lL, b, n, G); break;
        default: wave_pair<6, 3>(xs, wfl, wgl, fbl, gbl, oo, lL, b, n, G); break;
    }
}

// ---------------------------------------------------------------- skip projection
__global__ __launch_bounds__(256)
void k_skip(const u16* __restrict__ G, const float* __restrict__ xskip,
            const float* __restrict__ sw, const float* __restrict__ sb,
            float* __restrict__ outp)
{
    __shared__ alignas(16) u16 Gs[4096];
    __shared__ float swl[64 * 33];
    __shared__ float sbl[64];
    const int tid = threadIdx.x;
    const int b = blockIdx.x >> 7, n = blockIdx.x & 127;
    const u16* gb_ = G + (size_t)b * 524288 + n * 128;
    for (int p = 0; p < 2; ++p) {
        int chunk = p * 256 + tid, c = chunk >> 4, l8 = (chunk & 15) * 8;
        *(uint4*)&Gs[c * 128 + l8] = *(const uint4*)(gb_ + (size_t)c * 16384 + l8);
    }
    for (int i = tid; i < 2048; i += 256) swl[(i >> 5) * 33 + (i & 31)] = sw[i];
    if (tid < 64) sbl[tid] = sb[tid];
    __syncthreads();
    const int sg = (tid & 15) * 4, l0 = (tid >> 4) * 8;
    float acc[4][8];
    #pragma unroll
    for (int si = 0; si < 4; ++si) {
        float bv = sbl[sg + si];
        #pragma unroll
        for (int li = 0; li < 8; ++li) acc[si][li] = bv;
    }
    for (int c = 0; c < 32; ++c) {
        uint4 gv = *(const uint4*)&Gs[c * 128 + l0];
        float g[8];
        g[0] = __uint_as_float(gv.x << 16); g[1] = __uint_as_float(gv.x & 0xffff0000u);
        g[2] = __uint_as_float(gv.y << 16); g[3] = __uint_as_float(gv.y & 0xffff0000u);
        g[4] = __uint_as_float(gv.z << 16); g[5] = __uint_as_float(gv.z & 0xffff0000u);
        g[6] = __uint_as_float(gv.w << 16); g[7] = __uint_as_float(gv.w & 0xffff0000u);
        #pragma unroll
        for (int si = 0; si < 4; ++si) {
            float wv = swl[(sg + si) * 33 + c];
            #pragma unroll
            for (int li = 0; li < 8; ++li) acc[si][li] = __fmaf_rn(g[li], wv, acc[si][li]);
        }
    }
    #pragma unroll
    for (int si = 0; si < 4; ++si) {
        size_t e = ((size_t)(b * 64 + sg + si) * 128 + n) * 128 + l0;
        f32x4 x0 = *(const f32x4*)(xskip + e);
        f32x4 x1 = *(const f32x4*)(xskip + e + 4);
        f32x4 r0, r1;
        r0[0] = acc[si][0] + x0[0]; r0[1] = acc[si][1] + x0[1];
        r0[2] = acc[si][2] + x0[2]; r0[3] = acc[si][3] + x0[3];
        r1[0] = acc[si][4] + x1[0]; r1[1] = acc[si][5] + x1[1];
        r1[2] = acc[si][6] + x1[2]; r1[3] = acc[si][7] + x1[3];
        *(f32x4*)(outp + e)     = r0;
        *(f32x4*)(outp + e + 4) = r1;
    }
}

// ---------------------------------------------------------------- fused mix1+mix2 + x-residual + LN partial sums
__global__ __launch_bounds__(256)
void k_mix2ln(const u16* __restrict__ G,
              const u16* __restrict__ H1, const u16* __restrict__ H2,
              const u16* __restrict__ H1b, const u16* __restrict__ H2b,
              const float* __restrict__ mw1, const float* __restrict__ mb1,
              const float* __restrict__ mw2, const float* __restrict__ mb2,
              const float* __restrict__ x,
              float* __restrict__ Y, float* __restrict__ partial)
{
    __shared__ alignas(16) u16 Gs[4096], H1s[4096], H2s[4096], H1bs[4096], H2bs[4096];
    __shared__ float wSg[32 * 33], wS11[32 * 33], wS12[32 * 33], wS21[32 * 33], wS22[32 * 33];
    __shared__ float mbl[32];
    const int tid = threadIdx.x;
    const int b = blockIdx.x >> 7, xn = blockIdx.x & 127;
    size_t base = (size_t)b * 524288 + xn * 128;
    for (int p = 0; p < 2; ++p) {
        int chunk = p * 256 + tid, c = chunk >> 4, l8 = (chunk & 15) * 8;
        size_t src = base + (size_t)c * 16384 + l8;
        *(uint4*)&Gs[c * 128 + l8]   = *(const uint4*)(G + src);
        *(uint4*)&H1s[c * 128 + l8]  = *(const uint4*)(H1 + src);
        *(uint4*)&H2s[c * 128 + l8]  = *(const uint4*)(H2 + src);
        *(uint4*)&H1bs[c * 128 + l8] = *(const uint4*)(H1b + src);
        *(uint4*)&H2bs[c * 128 + l8] = *(const uint4*)(H2b + src);
    }
    for (int i = tid; i < 1024; i += 256) {
        int o = i >> 5, c = i & 31;
        int d = o * 33 + c;
        wSg[d]  = mw1[o * 96 + c] + mw2[o * 96 + c];
        wS11[d] = mw1[o * 96 + 32 + c];
        wS12[d] = mw1[o * 96 + 64 + c];
        wS21[d] = mw2[o * 96 + 32 + c];
        wS22[d] = mw2[o * 96 + 64 + c];
    }
    if (tid < 32) mbl[tid] = mb1[tid] + mb2[tid];
    __syncthreads();
    const int og = (tid & 7) * 4, l0 = (tid >> 3) * 4;
    float acc[4][4];
    #pragma unroll
    for (int oi = 0; oi < 4; ++oi) {
        float bv = mbl[og + oi];
        acc[oi][0] = bv; acc[oi][1] = bv; acc[oi][2] = bv; acc[oi][3] = bv;
    }
    for (int c = 0; c < 32; ++c) {
        uint2 ga = *(const uint2*)&Gs[c * 128 + l0];
        uint2 h1 = *(const uint2*)&H1s[c * 128 + l0];
        uint2 h2 = *(const uint2*)&H2s[c * 128 + l0];
        uint2 j1 = *(const uint2*)&H1bs[c * 128 + l0];
        uint2 j2 = *(const uint2*)&H2bs[c * 128 + l0];
        float gv[4], v1[4], v2[4], u1[4], u2[4];
        gv[0] = __uint_as_float(ga.x << 16); gv[1] = __uint_as_float(ga.x & 0xffff0000u);
        gv[2] = __uint_as_float(ga.y << 16); gv[3] = __uint_as_float(ga.y & 0xffff0000u);
        v1[0] = __uint_as_float(h1.x << 16); v1[1] = __uint_as_float(h1.x & 0xffff0000u);
        v1[2] = __uint_as_float(h1.y << 16); v1[3] = __uint_as_float(h1.y & 0xffff0000u);
        v2[0] = __uint_as_float(h2.x << 16); v2[1] = __uint_as_float(h2.x & 0xffff0000u);
        v2[2] = __uint_as_float(h2.y << 16); v2[3] = __uint_as_float(h2.y & 0xffff0000u);
        u1[0] = __uint_as_float(j1.x << 16); u1[1] = __uint_as_float(j1.x & 0xffff0000u);
        u1[2] = __uint_as_float(j1.y << 16); u1[3] = __uint_as_float(j1.y & 0xffff0000u);
        u2[0] = __uint_as_float(j2.x << 16); u2[1] = __uint_as_float(j2.x & 0xffff0000u);
        u2[2] = __uint_as_float(j2.y << 16); u2[3] = __uint_as_float(j2.y & 0xffff0000u);
        #pragma unroll
        for (int oi = 0; oi < 4; ++oi) {
            int d = (og + oi) * 33 + c;
            float a0 = wSg[d], a1 = wS11[d], a2 = wS12[d], a3 = wS21[d], a4 = wS22[d];
            #pragma unroll
            for (int li = 0; li < 4; ++li)
                acc[oi][li] += gv[li] * a0 + v1[li] * a1 + v2[li] * a2
                             + u1[li] * a3 + u2[li] * a4;
        }
    }
    float s = 0.f, ss = 0.f;
    #pragma unroll
    for (int oi = 0; oi < 4; ++oi) {
        size_t e = ((size_t)(b * 32 + og + oi) * 128 + xn) * 128 + l0;
        f32x4 xv = *(const f32x4*)(x + e);
        f32x4 yv;
        #pragma unroll
        for (int li = 0; li < 4; ++li) {
            float y = acc[oi][li] + xv[li];
            yv[li] = y;
            s += y; ss += y * y;
        }
        *(f32x4*)(Y + e) = yv;
    }
    #pragma unroll
    for (int o = 32; o > 0; o >>= 1) {
        s  += __shfl_down(s,  o, 64);
        ss += __shfl_down(ss, o, 64);
    }
    __shared__ float sred[8];
    int w = tid >> 6;
    if ((tid & 63) == 0) { sred[w * 2] = s; sred[w * 2 + 1] = ss; }
    __syncthreads();
    if (tid == 0) {
        partial[blockIdx.x * 2]     = sred[0] + sred[2] + sred[4] + sred[6];
        partial[blockIdx.x * 2 + 1] = sred[1] + sred[3] + sred[5] + sred[7];
    }
}

// ---------------------------------------------------------------- LayerNorm finalize
__global__ __launch_bounds__(256)
void k_lnnorm(const float* __restrict__ Y,
              const float* __restrict__ partial, const int* __restrict__ idxp,
              const float* __restrict__ lnw, const float* __restrict__ lnb,
              float* __restrict__ outx)
{
    const int tid = threadIdx.x;
    const int b = blockIdx.x >> 7, chunk = blockIdx.x & 127;
    float s = 0.f, ss = 0.f;
    if (tid < 128) {
        s  = partial[(b * 128 + tid) * 2];
        ss = partial[(b * 128 + tid) * 2 + 1];
    }
    #pragma unroll
    for (int o = 32; o > 0; o >>= 1) {
        s  += __shfl_down(s,  o, 64);
        ss += __shfl_down(ss, o, 64);
    }
    __shared__ float sred[4];
    __shared__ float mv[2];
    if ((tid & 63) == 0 && tid < 128) { sred[(tid >> 6) * 2] = s; sred[(tid >> 6) * 2 + 1] = ss; }
    __syncthreads();
    if (tid == 0) {
        float S = sred[0] + sred[2], SS = sred[1] + sred[3];
        float mean = S * (1.f / 524288.f);
        float var = SS * (1.f / 524288.f) - mean * mean;
        mv[0] = mean; mv[1] = rsqrtf(var + 1e-5f);
    }
    __syncthreads();
    const float mean = mv[0], rstd = mv[1];
    #pragma unroll
    for (int q = 0; q < 4; ++q) {
        int ib = chunk * 4096 + q * 1024 + tid * 4;
        size_t e = (size_t)b * 524288 + ib;
        f32x4 yv = *(const f32x4*)(Y + e);
        int c = ib >> 14, xn = (ib >> 7) & 127, l = ib & 127;
        int ix = idxp[xn];
        size_t we = ((size_t)c * 128 + ix) * 128 + l;
        f32x4 wv = *(const f32x4*)(lnw + we);
        f32x4 bv = *(const f32x4*)(lnb + we);
        f32x4 r;
        #pragma unroll
        for (int j = 0; j < 4; ++j)
            r[j] = (yv[j] - mean) * rstd * wv[j] + bv[j];
        *(f32x4*)(outx + e) = r;
    }
}

// ---------------------------------------------------------------- launcher
extern "C" void kernel_launch(void* const* d_in, const int* in_sizes, int n_in,
                              void* d_out, int out_size, void* d_ws, size_t ws_size,
                              hipStream_t stream)
{
    (void)in_sizes; (void)n_in; (void)out_size; (void)ws_size;
    const float* x      = (const float*)d_in[0];
    const float* xskip  = (const float*)d_in[1];
    const float* A      = (const float*)d_in[2];
    const int*   idxp   = (const int*)d_in[3];
    const float* fw2p = (const float*)d_in[4];  const float* fb2p = (const float*)d_in[5];
    const float* fw3p = (const float*)d_in[6];  const float* fb3p = (const float*)d_in[7];
    const float* fw6p = (const float*)d_in[8];  const float* fb6p = (const float*)d_in[9];
    const float* fw7p = (const float*)d_in[10]; const float* fb7p = (const float*)d_in[11];
    const float* gw2p = (const float*)d_in[12]; const float* gb2p = (const float*)d_in[13];
    const float* gw3p = (const float*)d_in[14]; const float* gb3p = (const float*)d_in[15];
    const float* gw6p = (const float*)d_in[16]; const float* gb6p = (const float*)d_in[17];
    const float* gw7p = (const float*)d_in[18]; const float* gb7p = (const float*)d_in[19];
    const float* sw   = (const float*)d_in[20]; const float* sb   = (const float*)d_in[21];
    const float* mp1_gw = (const float*)d_in[22]; const float* mp1_gb = (const float*)d_in[23];
    const float* mp1_mw = (const float*)d_in[24]; const float* mp1_mb = (const float*)d_in[25];
    const float* mp2_gw = (const float*)d_in[26]; const float* mp2_gb = (const float*)d_in[27];
    const float* mp2_mw = (const float*)d_in[28]; const float* mp2_mb = (const float*)d_in[29];
    const float* lnw = (const float*)d_in[30]; const float* lnb = (const float*)d_in[31];

    char* wsb = (char*)d_ws;
    float* out_x  = (float*)d_out;
    float* out_sk = out_x + 8388608;

    const size_t MB16 = 16777216, MB33 = 33554432;
    u16*   G    = (u16*)(wsb);
    u16*   H1   = (u16*)(wsb + MB16);
    u16*   H1b  = (u16*)(wsb + 2 * MB16);
    u16*   H2   = (u16*)(wsb + 3 * MB16);
    u16*   H2b  = (u16*)(wsb + 4 * MB16);
    u16*   Wb0  = (u16*)(wsb + 5 * MB16);
    u16*   Wb1  = (u16*)(wsb + 5 * MB16 + MB33);
    float* Yb   = (float*)Wb0;                      // reuse after hop-2 GEMM
    float* XW0a = (float*)(wsb + 5 * MB16 + 2 * MB33);
    float* XW0b = (float*)(wsb + 5 * MB16 + 2 * MB33 + 2097152);
    float* part = (float*)(wsb + 5 * MB16 + 2 * MB33 + 4194304);
    float* dd   = (float*)(wsb + 5 * MB16 + 2 * MB33 + 4194304 + 16384);
    float *dis1 = dd, *inv1 = dd + 128, *dis2 = dd + 256, *inv2 = dd + 384;

    k_prep<<<1, 128, 0, stream>>>(A, dis1, inv1, dis2, inv2);
    k_incep<<<2048, 256, 0, stream>>>(x, fw2p, fw3p, fw6p, fw7p, fb2p, fb3p, fb6p, fb7p,
                                      gw2p, gw3p, gw6p, gw7p, gb2p, gb3p, gb6p, gb7p, G);
    k_skip<<<2048, 256, 0, stream>>>(G, xskip, sw, sb, out_sk);

    dim3 gg2(32, 16, 2);
    // hop 1 (both mixprops)
    k_wcvt2<<<16384, 256, 0, stream>>>(mp1_gw, mp2_gw, Wb0, Wb1);
    k_gemm2g<<<gg2, 256, 0, stream>>>(G, G, Wb0, Wb1, G, mp1_gb, mp2_gb,
                                      H1, H1b, XW0a, XW0b);
    k_gcnfix<<<1024, 256, 0, stream>>>(XW0a, XW0b, G, A, dis1, inv1, dis2, inv2,
                                       mp1_gb, mp2_gb, H1, H1b);
    // hop 2 (both mixprops)
    k_wcvt2<<<16384, 256, 0, stream>>>(mp1_gw + MB16, mp2_gw + MB16, Wb0, Wb1);
    k_gemm2g<<<gg2, 256, 0, stream>>>(H1, H1b, Wb0, Wb1, G, mp1_gb + 4096, mp2_gb + 4096,
                                      H2, H2b, XW0a, XW0b);
    k_gcnfix<<<1024, 256, 0, stream>>>(XW0a, XW0b, G, A, dis1, inv1, dis2, inv2,
                                       mp1_gb + 4096, mp2_gb + 4096, H2, H2b);
    // fused channel-mix + residual + LN
    k_mix2ln<<<2048, 256, 0, stream>>>(G, H1, H2, H1b, H2b, mp1_mw, mp1_mb,
                                       mp2_mw, mp2_mb, x, Yb, part);
    k_lnnorm<<<2048, 256, 0, stream>>>(Yb, part, idxp, lnw, lnb, out_x);
}

// Round 6
// 719.651 us; speedup vs baseline: 1.4600x; 1.0263x over previous
//
#include <hip/hip_runtime.h>
#include <stdint.h>

typedef unsigned short u16;
typedef unsigned int   u32;
typedef __attribute__((ext_vector_type(4))) float f32x4;
typedef __attribute__((ext_vector_type(8))) short bf16x8;

__device__ __forceinline__ u16 f2bf(float f) {
    u32 i = __float_as_uint(f);
    u32 r = (i + 0x7fffu + ((i >> 16) & 1u)) >> 16;   // RNE
    return (u16)r;
}
__device__ __forceinline__ float bf2f(u16 u) {
    return __uint_as_float(((u32)u) << 16);
}
__device__ __forceinline__ u32 cvt2bf(float a, float b) {
    u32 r;
    asm("v_cvt_pk_bf16_f32 %0, %1, %2" : "=v"(r) : "v"(a), "v"(b));
    return r;
}

#define GLOAD16(g, l) __builtin_amdgcn_global_load_lds( \
    (const __attribute__((address_space(1))) void*)(g), \
    (__attribute__((address_space(3))) void*)(l), 16, 0, 0)

// ---------------------------------------------------------------- prep: degrees
__global__ void k_prep(const float* __restrict__ A, float* dis1, float* inv1,
                       float* dis2, float* inv2)
{
    int r = threadIdx.x;
    if (r >= 128) return;
    int cc = 0, cr = 0;
    for (int j = 0; j < 128; ++j) {
        if (j == r) continue;
        if (A[(j << 7) + r] != 0.f) cc++;   // column count (mp1)
        if (A[(r << 7) + j] != 0.f) cr++;   // row count (mp2, A^T)
    }
    float d1 = 1.f + (float)cc, d2 = 1.f + (float)cr;
    dis1[r] = rsqrtf(d1); inv1[r] = 1.f / d1;
    dis2[r] = rsqrtf(d2); inv2[r] = 1.f / d2;
}

// ---------------------------------------------------------------- weight f32 -> bf16 (both mixprops, one hop)
__global__ __launch_bounds__(256)
void k_wcvt2(const float* __restrict__ W0, const float* __restrict__ W1,
             u16* __restrict__ Wb0, u16* __restrict__ Wb1)
{
    int half = blockIdx.x >> 13;                      // grid 16384: 8192 per matrix
    const float* W = half ? W1 : W0;
    u16* Wb = half ? Wb1 : Wb0;
    size_t e = ((size_t)(blockIdx.x & 8191) * 256 + threadIdx.x) * 8;
    f32x4 a = *(const f32x4*)(W + e);
    f32x4 b = *(const f32x4*)(W + e + 4);
    uint4 r;
    r.x = cvt2bf(a[0], a[1]); r.y = cvt2bf(a[2], a[3]);
    r.z = cvt2bf(b[0], b[1]); r.w = cvt2bf(b[2], b[3]);
    *(uint4*)(Wb + e) = r;
}

// ---------------------------------------------------------------- GEMM + fused GCN-self epilogue
// 256x256 tile, BK=32, 512 threads (8 waves as 2x4), 4-deep LDS rotation,
// prefetch distance 3, counted vmcnt (never 0 mid-loop), swizzled LDS.
// Dual problem (z from XCD-swizzled flat blockIdx).
// Epilogue: H = bf16(XW + gb[o] + 0.05*G) (rows<128 later fixed by k_gcnfix);
// bm==0 && wr==0 also dumps raw f32 XW rows 0..127 to XW0.
__global__ __launch_bounds__(512, 1)
void k_gemm2g(const u16* __restrict__ A0, const u16* __restrict__ A1,
              const u16* __restrict__ B0, const u16* __restrict__ B1,
              const u16* __restrict__ Gres,
              const float* __restrict__ gb0, const float* __restrict__ gb1,
              u16* __restrict__ Ha, u16* __restrict__ Hb,
              float* __restrict__ XW0a, float* __restrict__ XW0b)
{
    __shared__ alignas(16) u16 LDS[65536];     // 128 KB: 4 bufs x (A 16KB + B 16KB)
    const int NT = 128;                         // K / BK = 4096 / 32
    const int tid  = threadIdx.x;
    const int lane = tid & 63;
    const int wid  = tid >> 6;                  // 0..7
    const int wr = wid >> 2, wc = wid & 3;      // 2 x 4 wave grid

    // 256 WGs flat; bijective XCD swizzle (256 % 8 == 0, cpx = 32)
    const int bid = blockIdx.x;
    const int swz = (bid & 7) * 32 + (bid >> 3);
    const int z   = swz >> 7;                   // problem select (128 WGs each)
    const int rem = swz & 127;
    const int bm = (rem >> 4) * 256;            // 8 m-tiles (M = 2048)
    const int bn = (rem & 15) * 256;            // 16 n-tiles (N = 4096)

    const u16* Ap = (z ? A1 : A0) + (size_t)bm * 4096;
    const u16* Bp = (z ? B1 : B0) + (size_t)bn * 4096;

    // per-thread staging chunks: ch in {tid, tid+512} over 1024 16B-chunks/tile
    // physical LDS chunk ch -> row r = ch>>2, phys slot = ch&3;
    // logical slot = phys ^ ((r>>1)&3)  (bank-spread swizzle, involution)
    // ds_read fragment offsets (u16 units), swizzle applied once:
    int aoff[8];
    #pragma unroll
    for (int i = 0; i < 8; ++i) {
        int ra = wr * 128 + i * 16 + (lane & 15);
        int sp = (lane >> 4) ^ ((ra >> 1) & 3);
        aoff[i] = ra * 32 + sp * 8;
    }
    int boff[4];
    #pragma unroll
    for (int j = 0; j < 4; ++j) {
        int rb = wc * 64 + j * 16 + (lane & 15);
        int sp = (lane >> 4) ^ ((rb >> 1) & 3);
        boff[j] = rb * 32 + sp * 8;
    }

    f32x4 acc[8][4] = {};

    auto stage = [&](int t) {
        const int k0  = t << 5;
        const int buf = (t & 3) << 14;          // u16 offset (16384 per buf)
        #pragma unroll
        for (int h = 0; h < 2; ++h) {
            const int ch = tid + h * 512;
            const int r  = ch >> 2;
            const int sl = (ch & 3) ^ ((r >> 1) & 3);
            GLOAD16(Ap + (size_t)r * 4096 + k0 + sl * 8, LDS + buf + ch * 8);
            GLOAD16(Bp + (size_t)r * 4096 + k0 + sl * 8, LDS + buf + 8192 + ch * 8);
        }
    };
    auto compute = [&](int t) {
        const u16* base = LDS + ((t & 3) << 14);
        bf16x8 af[8], bv[4];
        #pragma unroll
        for (int i = 0; i < 8; ++i) af[i] = *(const bf16x8*)(base + aoff[i]);
        #pragma unroll
        for (int j = 0; j < 4; ++j) bv[j] = *(const bf16x8*)(base + 8192 + boff[j]);
        #pragma unroll
        for (int i = 0; i < 8; ++i)
            #pragma unroll
            for (int j = 0; j < 4; ++j)
                acc[i][j] = __builtin_amdgcn_mfma_f32_16x16x32_bf16(af[i], bv[j], acc[i][j], 0, 0, 0);
    };

    // prologue: fill pipeline 3 deep, wait tile 0 only (8 of 12 loads may fly)
    stage(0); stage(1); stage(2);
    asm volatile("s_waitcnt vmcnt(8)" ::: "memory");
    __syncthreads();

    int t = 0;
    for (; t < NT - 3; ++t) {
        stage(t + 3);
        compute(t);
        asm volatile("s_waitcnt vmcnt(8)" ::: "memory");   // drain tile t+1 only
        __syncthreads();
    }
    compute(t);                                             // t = NT-3
    asm volatile("s_waitcnt vmcnt(4)" ::: "memory");
    __syncthreads(); ++t;
    compute(t);                                             // t = NT-2
    asm volatile("s_waitcnt vmcnt(0)" ::: "memory");
    __syncthreads(); ++t;
    compute(t);                                             // t = NT-1

    // ---------------- epilogue
    const int orow = (lane >> 4) * 4, ocol = lane & 15;
    const float* gbv = z ? gb1 : gb0;
    u16* H = z ? Hb : Ha;

    #pragma unroll
    for (int j = 0; j < 4; ++j) {
        const int o = bn + wc * 64 + j * 16 + ocol;
        const float gbo = gbv[o];
        #pragma unroll
        for (int i = 0; i < 8; ++i) {
            const int rbase = bm + wr * 128 + i * 16 + orow;
            #pragma unroll
            for (int v = 0; v < 4; ++v) {
                const size_t e = (size_t)(rbase + v) * 4096 + o;
                float g = bf2f(Gres[e]);
                H[e] = f2bf(__fmaf_rn(0.05f, g, acc[i][j][v] + gbo));
            }
        }
    }
    if (bm == 0 && wr == 0) {
        float* XW0 = z ? XW0b : XW0a;
        #pragma unroll
        for (int i = 0; i < 8; ++i) {
            #pragma unroll
            for (int j = 0; j < 4; ++j) {
                float* cp = XW0 + (size_t)(i * 16 + orow) * 4096 + (bn + wc * 64 + j * 16 + ocol);
                #pragma unroll
                for (int v = 0; v < 4; ++v)
                    cp[(size_t)v * 4096] = acc[i][j][v];
            }
        }
    }
}

// ---------------------------------------------------------------- GCN fixup rows < 128 (both problems)
__global__ __launch_bounds__(256)
void k_gcnfix(const float* __restrict__ XW0a, const float* __restrict__ XW0b,
              const u16* __restrict__ G, const float* __restrict__ Af,
              const float* __restrict__ dis1, const float* __restrict__ inv1,
              const float* __restrict__ dis2, const float* __restrict__ inv2,
              const float* __restrict__ gb0, const float* __restrict__ gb1,
              u16* __restrict__ Ha, u16* __restrict__ Hb)
{
    const int prob = blockIdx.x >> 9;          // 0: mp1 (A), 1: mp2 (A^T)
    const int rem  = blockIdx.x & 511;
    const int t4 = rem * 256 + threadIdx.x;
    const int r = t4 >> 10, og = (t4 & 1023) << 2;
    const float* XW0 = prob ? XW0b : XW0a;
    const float* dis = prob ? dis2 : dis1;
    const float* inv = prob ? inv2 : inv1;
    const float* gb  = prob ? gb1  : gb0;
    u16* H = prob ? Hb : Ha;

    const size_t e = ((size_t)r << 12) + og;
    f32x4 xw = *(const f32x4*)(XW0 + e);
    f32x4 s = {0.f, 0.f, 0.f, 0.f};
    for (int j = 0; j < 128; ++j) {
        float av = prob ? Af[(r << 7) + j] : Af[(j << 7) + r];
        float wv = ((av != 0.f) && (j != r)) ? dis[j] : 0.f;
        f32x4 xv = *(const f32x4*)(XW0 + ((size_t)j << 12) + og);
        #pragma unroll
        for (int q = 0; q < 4; ++q) s[q] = __fmaf_rn(wv, xv[q], s[q]);
    }
    const float iv = inv[r], dr = dis[r];
    f32x4 gb4 = *(const f32x4*)(gb + og);
    uint2 gv = *(const uint2*)(G + e);
    float g0 = __uint_as_float(gv.x << 16), g1 = __uint_as_float(gv.x & 0xffff0000u);
    float g2 = __uint_as_float(gv.y << 16), g3 = __uint_as_float(gv.y & 0xffff0000u);
    float y0 = __fmaf_rn(0.05f, g0, __fmaf_rn(dr, s[0], xw[0] * iv) + gb4[0]);
    float y1 = __fmaf_rn(0.05f, g1, __fmaf_rn(dr, s[1], xw[1] * iv) + gb4[1]);
    float y2 = __fmaf_rn(0.05f, g2, __fmaf_rn(dr, s[2], xw[2] * iv) + gb4[2]);
    float y3 = __fmaf_rn(0.05f, g3, __fmaf_rn(dr, s[3], xw[3] * iv) + gb4[3]);
    uint2 rr;
    rr.x = cvt2bf(y0, y1);
    rr.y = cvt2bf(y2, y3);
    *(uint2*)(H + e) = rr;
}

// ---------------------------------------------------------------- inception + gate (wave-balanced)
__device__ __forceinline__ constexpr int wbase_of(int k) {
    return k == 2 ? 0 : k == 3 ? 520 : k == 6 ? 1296 : 2840;
}
__device__ __forceinline__ constexpr int ob_of(int k) {
    return k == 2 ? 0 : k == 3 ? 8 : k == 6 ? 16 : 24;
}

template<int K_>
__device__ __forceinline__ void conv_phase(const float* __restrict__ xsb,
                                           const float* __restrict__ wfp,
                                           const float* __restrict__ wgp,
                                           float fb, float gb,
                                           u16* __restrict__ Gp)
{
    float accf[8], accg[8];
    #pragma unroll
    for (int i = 0; i < 8; ++i) { accf[i] = fb; accg[i] = gb; }
    for (int c = 0; c < 32; ++c) {
        float xw[24];
        const float* xr = xsb + c * 144;
        #pragma unroll
        for (int q = 0; q < 6; ++q) {
            f32x4 v = *(const f32x4*)(xr + q * 4);
            xw[q * 4 + 0] = v[0]; xw[q * 4 + 1] = v[1];
            xw[q * 4 + 2] = v[2]; xw[q * 4 + 3] = v[3];
        }
        float wfj[K_], wgj[K_];
        const float* wfc = wfp + c * K_;
        const float* wgc = wgp + c * K_;
        #pragma unroll
        for (int j = 0; j < K_; ++j) { wfj[j] = wfc[j]; wgj[j] = wgc[j]; }
        #pragma unroll
        for (int li = 0; li < 8; ++li) {
            #pragma unroll
            for (int j = 0; j < K_; ++j) {
                float xv = xw[li + 8 - (K_ - 1) + 2 * j];
                accf[li] = __fmaf_rn(xv, wfj[j], accf[li]);
                accg[li] = __fmaf_rn(xv, wgj[j], accg[li]);
            }
        }
    }
    u16 o8[8];
    #pragma unroll
    for (int i = 0; i < 8; ++i) {
        float e2 = __expf(2.f * accf[i]);
        float th = 1.f - __fdividef(2.f, e2 + 1.f);
        float sg = __fdividef(1.f, 1.f + __expf(-accg[i]));
        o8[i] = f2bf(th * sg);
    }
    uint4 u;
    u.x = o8[0] | ((u32)o8[1] << 16); u.y = o8[2] | ((u32)o8[3] << 16);
    u.z = o8[4] | ((u32)o8[5] << 16); u.w = o8[6] | ((u32)o8[7] << 16);
    *(uint4*)Gp = u;
}

template<int KA, int KB>
__device__ __forceinline__ void wave_pair(const float* __restrict__ xs,
                                          const float* __restrict__ wfl,
                                          const float* __restrict__ wgl,
                                          const float* __restrict__ fbl,
                                          const float* __restrict__ gbl,
                                          int oo, int lL, int b, int n,
                                          u16* __restrict__ G)
{
    {
        constexpr int BS = wbase_of(KA), ST = 32 * KA + 1, OB = ob_of(KA);
        const int o = OB + oo, l0 = lL * 8;
        conv_phase<KA>(xs + l0, wfl + BS + oo * ST, wgl + BS + oo * ST,
                       fbl[o], gbl[o],
                       G + (((size_t)(b * 32 + o) * 128 + n) * 128 + l0));
    }
    {
        constexpr int BS = wbase_of(KB), ST = 32 * KB + 1, OB = ob_of(KB);
        const int o = OB + oo, l0 = 64 + lL * 8;
        conv_phase<KB>(xs + l0, wfl + BS + oo * ST, wgl + BS + oo * ST,
                       fbl[o], gbl[o],
                       G + (((size_t)(b * 32 + o) * 128 + n) * 128 + l0));
    }
}

__global__ __launch_bounds__(256)
void k_incep(const float* __restrict__ x,
             const float* __restrict__ fw2p, const float* __restrict__ fw3p,
             const float* __restrict__ fw6p, const float* __restrict__ fw7p,
             const float* __restrict__ fb2p, const float* __restrict__ fb3p,
             const float* __restrict__ fb6p, const float* __restrict__ fb7p,
             const float* __restrict__ gw2p, const float* __restrict__ gw3p,
             const float* __restrict__ gw6p, const float* __restrict__ gw7p,
             const float* __restrict__ gb2p, const float* __restrict__ gb3p,
             const float* __restrict__ gb6p, const float* __restrict__ gb7p,
             u16* __restrict__ G)
{
    __shared__ alignas(16) float xs[32 * 144];
    __shared__ float wfl[4640], wgl[4640];
    __shared__ float fbl[32], gbl[32];
    const int tid = threadIdx.x;
    const int b = blockIdx.x >> 7, n = blockIdx.x & 127;

    for (int i = tid; i < 32 * 144; i += 256) xs[i] = 0.f;
    for (int g = tid; g < 4608; g += 256) {
        int rel, k, woff;
        const float *pf, *pg;
        if (g < 512)       { rel = g;        k = 2; woff = 0;    pf = fw2p; pg = gw2p; }
        else if (g < 1280) { rel = g - 512;  k = 3; woff = 520;  pf = fw3p; pg = gw3p; }
        else if (g < 2816) { rel = g - 1280; k = 6; woff = 1296; pf = fw6p; pg = gw6p; }
        else               { rel = g - 2816; k = 7; woff = 2840; pf = fw7p; pg = gw7p; }
        int ck = 32 * k;
        int oo = rel / ck, rem = rel % ck;
        int dst = woff + oo * (ck + 1) + rem;
        wfl[dst] = pf[rel];
        wgl[dst] = pg[rel];
    }
    if (tid < 32) {
        int br = tid >> 3, oo = tid & 7;
        const float* pf = br == 0 ? fb2p : br == 1 ? fb3p : br == 2 ? fb6p : fb7p;
        const float* pg = br == 0 ? gb2p : br == 1 ? gb3p : br == 2 ? gb6p : gb7p;
        fbl[tid] = pf[oo]; gbl[tid] = pg[oo];
    }
    __syncthreads();
    const float* xb = x + (size_t)b * 524288 + n * 128;
    for (int p = 0; p < 4; ++p) {
        int chunk = p * 256 + tid;
        int c = chunk >> 5, l4 = (chunk & 31) * 4;
        *(f32x4*)&xs[c * 144 + 8 + l4] = *(const f32x4*)(xb + (size_t)c * 16384 + l4);
    }
    __syncthreads();

    const int w = tid >> 6, lane = tid & 63;
    const int oo = lane >> 3, lL = lane & 7;
    switch (w) {
        case 0:  wave_pair<2, 7>(xs, wfl, wgl, fbl, gbl, oo, lL, b, n, G); break;
        case 1:  wave_pair<7, 2>(xs, wfl, wgl, fbl, gbl, oo, lL, b, n, G); break;
        case 2:  wave_pair<3, 6>(xs, wfl, wgl, fbl, gbl, oo, lL, b, n, G); break;
        default: wave_pair<6, 3>(xs, wfl, wgl, fbl, gbl, oo, lL, b, n, G); break;
    }
}

// ---------------------------------------------------------------- skip projection
__global__ __launch_bounds__(256)
void k_skip(const u16* __restrict__ G, const float* __restrict__ xskip,
            const float* __restrict__ sw, const float* __restrict__ sb,
            float* __restrict__ outp)
{
    __shared__ alignas(16) u16 Gs[4096];
    __shared__ float swl[64 * 33];
    __shared__ float sbl[64];
    const int tid = threadIdx.x;
    const int b = blockIdx.x >> 7, n = blockIdx.x & 127;
    const u16* gb_ = G + (size_t)b * 524288 + n * 128;
    for (int p = 0; p < 2; ++p) {
        int chunk = p * 256 + tid, c = chunk >> 4, l8 = (chunk & 15) * 8;
        *(uint4*)&Gs[c * 128 + l8] = *(const uint4*)(gb_ + (size_t)c * 16384 + l8);
    }
    for (int i = tid; i < 2048; i += 256) swl[(i >> 5) * 33 + (i & 31)] = sw[i];
    if (tid < 64) sbl[tid] = sb[tid];
    __syncthreads();
    const int sg = (tid & 15) * 4, l0 = (tid >> 4) * 8;
    float acc[4][8];
    #pragma unroll
    for (int si = 0; si < 4; ++si) {
        float bv = sbl[sg + si];
        #pragma unroll
        for (int li = 0; li < 8; ++li) acc[si][li] = bv;
    }
    for (int c = 0; c < 32; ++c) {
        uint4 gv = *(const uint4*)&Gs[c * 128 + l0];
        float g[8];
        g[0] = __uint_as_float(gv.x << 16); g[1] = __uint_as_float(gv.x & 0xffff0000u);
        g[2] = __uint_as_float(gv.y << 16); g[3] = __uint_as_float(gv.y & 0xffff0000u);
        g[4] = __uint_as_float(gv.z << 16); g[5] = __uint_as_float(gv.z & 0xffff0000u);
        g[6] = __uint_as_float(gv.w << 16); g[7] = __uint_as_float(gv.w & 0xffff0000u);
        #pragma unroll
        for (int si = 0; si < 4; ++si) {
            float wv = swl[(sg + si) * 33 + c];
            #pragma unroll
            for (int li = 0; li < 8; ++li) acc[si][li] = __fmaf_rn(g[li], wv, acc[si][li]);
        }
    }
    #pragma unroll
    for (int si = 0; si < 4; ++si) {
        size_t e = ((size_t)(b * 64 + sg + si) * 128 + n) * 128 + l0;
        f32x4 x0 = *(const f32x4*)(xskip + e);
        f32x4 x1 = *(const f32x4*)(xskip + e + 4);
        f32x4 r0, r1;
        r0[0] = acc[si][0] + x0[0]; r0[1] = acc[si][1] + x0[1];
        r0[2] = acc[si][2] + x0[2]; r0[3] = acc[si][3] + x0[3];
        r1[0] = acc[si][4] + x1[0]; r1[1] = acc[si][5] + x1[1];
        r1[2] = acc[si][6] + x1[2]; r1[3] = acc[si][7] + x1[3];
        *(f32x4*)(outp + e)     = r0;
        *(f32x4*)(outp + e + 4) = r1;
    }
}

// ---------------------------------------------------------------- fused mix1+mix2 + x-residual + LN partial sums
__global__ __launch_bounds__(256)
void k_mix2ln(const u16* __restrict__ G,
              const u16* __restrict__ H1, const u16* __restrict__ H2,
              const u16* __restrict__ H1b, const u16* __restrict__ H2b,
              const float* __restrict__ mw1, const float* __restrict__ mb1,
              const float* __restrict__ mw2, const float* __restrict__ mb2,
              const float* __restrict__ x,
              float* __restrict__ Y, float* __restrict__ partial)
{
    __shared__ alignas(16) u16 Gs[4096], H1s[4096], H2s[4096], H1bs[4096], H2bs[4096];
    __shared__ float wSg[32 * 33], wS11[32 * 33], wS12[32 * 33], wS21[32 * 33], wS22[32 * 33];
    __shared__ float mbl[32];
    const int tid = threadIdx.x;
    const int b = blockIdx.x >> 7, xn = blockIdx.x & 127;
    size_t base = (size_t)b * 524288 + xn * 128;
    for (int p = 0; p < 2; ++p) {
        int chunk = p * 256 + tid, c = chunk >> 4, l8 = (chunk & 15) * 8;
        size_t src = base + (size_t)c * 16384 + l8;
        *(uint4*)&Gs[c * 128 + l8]   = *(const uint4*)(G + src);
        *(uint4*)&H1s[c * 128 + l8]  = *(const uint4*)(H1 + src);
        *(uint4*)&H2s[c * 128 + l8]  = *(const uint4*)(H2 + src);
        *(uint4*)&H1bs[c * 128 + l8] = *(const uint4*)(H1b + src);
        *(uint4*)&H2bs[c * 128 + l8] = *(const uint4*)(H2b + src);
    }
    for (int i = tid; i < 1024; i += 256) {
        int o = i >> 5, c = i & 31;
        int d = o * 33 + c;
        wSg[d]  = mw1[o * 96 + c] + mw2[o * 96 + c];
        wS11[d] = mw1[o * 96 + 32 + c];
        wS12[d] = mw1[o * 96 + 64 + c];
        wS21[d] = mw2[o * 96 + 32 + c];
        wS22[d] = mw2[o * 96 + 64 + c];
    }
    if (tid < 32) mbl[tid] = mb1[tid] + mb2[tid];
    __syncthreads();
    const int og = (tid & 7) * 4, l0 = (tid >> 3) * 4;
    float acc[4][4];
    #pragma unroll
    for (int oi = 0; oi < 4; ++oi) {
        float bv = mbl[og + oi];
        acc[oi][0] = bv; acc[oi][1] = bv; acc[oi][2] = bv; acc[oi][3] = bv;
    }
    for (int c = 0; c < 32; ++c) {
        uint2 ga = *(const uint2*)&Gs[c * 128 + l0];
        uint2 h1 = *(const uint2*)&H1s[c * 128 + l0];
        uint2 h2 = *(const uint2*)&H2s[c * 128 + l0];
        uint2 j1 = *(const uint2*)&H1bs[c * 128 + l0];
        uint2 j2 = *(const uint2*)&H2bs[c * 128 + l0];
        float gv[4], v1[4], v2[4], u1[4], u2[4];
        gv[0] = __uint_as_float(ga.x << 16); gv[1] = __uint_as_float(ga.x & 0xffff0000u);
        gv[2] = __uint_as_float(ga.y << 16); gv[3] = __uint_as_float(ga.y & 0xffff0000u);
        v1[0] = __uint_as_float(h1.x << 16); v1[1] = __uint_as_float(h1.x & 0xffff0000u);
        v1[2] = __uint_as_float(h1.y << 16); v1[3] = __uint_as_float(h1.y & 0xffff0000u);
        v2[0] = __uint_as_float(h2.x << 16); v2[1] = __uint_as_float(h2.x & 0xffff0000u);
        v2[2] = __uint_as_float(h2.y << 16); v2[3] = __uint_as_float(h2.y & 0xffff0000u);
        u1[0] = __uint_as_float(j1.x << 16); u1[1] = __uint_as_float(j1.x & 0xffff0000u);
        u1[2] = __uint_as_float(j1.y << 16); u1[3] = __uint_as_float(j1.y & 0xffff0000u);
        u2[0] = __uint_as_float(j2.x << 16); u2[1] = __uint_as_float(j2.x & 0xffff0000u);
        u2[2] = __uint_as_float(j2.y << 16); u2[3] = __uint_as_float(j2.y & 0xffff0000u);
        #pragma unroll
        for (int oi = 0; oi < 4; ++oi) {
            int d = (og + oi) * 33 + c;
            float a0 = wSg[d], a1 = wS11[d], a2 = wS12[d], a3 = wS21[d], a4 = wS22[d];
            #pragma unroll
            for (int li = 0; li < 4; ++li)
                acc[oi][li] += gv[li] * a0 + v1[li] * a1 + v2[li] * a2
                             + u1[li] * a3 + u2[li] * a4;
        }
    }
    float s = 0.f, ss = 0.f;
    #pragma unroll
    for (int oi = 0; oi < 4; ++oi) {
        size_t e = ((size_t)(b * 32 + og + oi) * 128 + xn) * 128 + l0;
        f32x4 xv = *(const f32x4*)(x + e);
        f32x4 yv;
        #pragma unroll
        for (int li = 0; li < 4; ++li) {
            float y = acc[oi][li] + xv[li];
            yv[li] = y;
            s += y; ss += y * y;
        }
        *(f32x4*)(Y + e) = yv;
    }
    #pragma unroll
    for (int o = 32; o > 0; o >>= 1) {
        s  += __shfl_down(s,  o, 64);
        ss += __shfl_down(ss, o, 64);
    }
    __shared__ float sred[8];
    int w = tid >> 6;
    if ((tid & 63) == 0) { sred[w * 2] = s; sred[w * 2 + 1] = ss; }
    __syncthreads();
    if (tid == 0) {
        partial[blockIdx.x * 2]     = sred[0] + sred[2] + sred[4] + sred[6];
        partial[blockIdx.x * 2 + 1] = sred[1] + sred[3] + sred[5] + sred[7];
    }
}

// ---------------------------------------------------------------- LayerNorm finalize
__global__ __launch_bounds__(256)
void k_lnnorm(const float* __restrict__ Y,
              const float* __restrict__ partial, const int* __restrict__ idxp,
              const float* __restrict__ lnw, const float* __restrict__ lnb,
              float* __restrict__ outx)
{
    const int tid = threadIdx.x;
    const int b = blockIdx.x >> 7, chunk = blockIdx.x & 127;
    float s = 0.f, ss = 0.f;
    if (tid < 128) {
        s  = partial[(b * 128 + tid) * 2];
        ss = partial[(b * 128 + tid) * 2 + 1];
    }
    #pragma unroll
    for (int o = 32; o > 0; o >>= 1) {
        s  += __shfl_down(s,  o, 64);
        ss += __shfl_down(ss, o, 64);
    }
    __shared__ float sred[4];
    __shared__ float mv[2];
    if ((tid & 63) == 0 && tid < 128) { sred[(tid >> 6) * 2] = s; sred[(tid >> 6) * 2 + 1] = ss; }
    __syncthreads();
    if (tid == 0) {
        float S = sred[0] + sred[2], SS = sred[1] + sred[3];
        float mean = S * (1.f / 524288.f);
        float var = SS * (1.f / 524288.f) - mean * mean;
        mv[0] = mean; mv[1] = rsqrtf(var + 1e-5f);
    }
    __syncthreads();
    const float mean = mv[0], rstd = mv[1];
    #pragma unroll
    for (int q = 0; q < 4; ++q) {
        int ib = chunk * 4096 + q * 1024 + tid * 4;
        size_t e = (size_t)b * 524288 + ib;
        f32x4 yv = *(const f32x4*)(Y + e);
        int c = ib >> 14, xn = (ib >> 7) & 127, l = ib & 127;
        int ix = idxp[xn];
        size_t we = ((size_t)c * 128 + ix) * 128 + l;
        f32x4 wv = *(const f32x4*)(lnw + we);
        f32x4 bv = *(const f32x4*)(lnb + we);
        f32x4 r;
        #pragma unroll
        for (int j = 0; j < 4; ++j)
            r[j] = (yv[j] - mean) * rstd * wv[j] + bv[j];
        *(f32x4*)(outx + e) = r;
    }
}

// ---------------------------------------------------------------- launcher
extern "C" void kernel_launch(void* const* d_in, const int* in_sizes, int n_in,
                              void* d_out, int out_size, void* d_ws, size_t ws_size,
                              hipStream_t stream)
{
    (void)in_sizes; (void)n_in; (void)out_size; (void)ws_size;
    const float* x      = (const float*)d_in[0];
    const float* xskip  = (const float*)d_in[1];
    const float* A      = (const float*)d_in[2];
    const int*   idxp   = (const int*)d_in[3];
    const float* fw2p = (const float*)d_in[4];  const float* fb2p = (const float*)d_in[5];
    const float* fw3p = (const float*)d_in[6];  const float* fb3p = (const float*)d_in[7];
    const float* fw6p = (const float*)d_in[8];  const float* fb6p = (const float*)d_in[9];
    const float* fw7p = (const float*)d_in[10]; const float* fb7p = (const float*)d_in[11];
    const float* gw2p = (const float*)d_in[12]; const float* gb2p = (const float*)d_in[13];
    const float* gw3p = (const float*)d_in[14]; const float* gb3p = (const float*)d_in[15];
    const float* gw6p = (const float*)d_in[16]; const float* gb6p = (const float*)d_in[17];
    const float* gw7p = (const float*)d_in[18]; const float* gb7p = (const float*)d_in[19];
    const float* sw   = (const float*)d_in[20]; const float* sb   = (const float*)d_in[21];
    const float* mp1_gw = (const float*)d_in[22]; const float* mp1_gb = (const float*)d_in[23];
    const float* mp1_mw = (const float*)d_in[24]; const float* mp1_mb = (const float*)d_in[25];
    const float* mp2_gw = (const float*)d_in[26]; const float* mp2_gb = (const float*)d_in[27];
    const float* mp2_mw = (const float*)d_in[28]; const float* mp2_mb = (const float*)d_in[29];
    const float* lnw = (const float*)d_in[30]; const float* lnb = (const float*)d_in[31];

    char* wsb = (char*)d_ws;
    float* out_x  = (float*)d_out;
    float* out_sk = out_x + 8388608;

    const size_t MB16 = 16777216, MB33 = 33554432;
    u16*   G    = (u16*)(wsb);
    u16*   H1   = (u16*)(wsb + MB16);
    u16*   H1b  = (u16*)(wsb + 2 * MB16);
    u16*   H2   = (u16*)(wsb + 3 * MB16);
    u16*   H2b  = (u16*)(wsb + 4 * MB16);
    u16*   Wb0  = (u16*)(wsb + 5 * MB16);
    u16*   Wb1  = (u16*)(wsb + 5 * MB16 + MB33);
    float* Yb   = (float*)Wb0;                      // reuse after hop-2 GEMM
    float* XW0a = (float*)(wsb + 5 * MB16 + 2 * MB33);
    float* XW0b = (float*)(wsb + 5 * MB16 + 2 * MB33 + 2097152);
    float* part = (float*)(wsb + 5 * MB16 + 2 * MB33 + 4194304);
    float* dd   = (float*)(wsb + 5 * MB16 + 2 * MB33 + 4194304 + 16384);
    float *dis1 = dd, *inv1 = dd + 128, *dis2 = dd + 256, *inv2 = dd + 384;

    k_prep<<<1, 128, 0, stream>>>(A, dis1, inv1, dis2, inv2);
    k_incep<<<2048, 256, 0, stream>>>(x, fw2p, fw3p, fw6p, fw7p, fb2p, fb3p, fb6p, fb7p,
                                      gw2p, gw3p, gw6p, gw7p, gb2p, gb3p, gb6p, gb7p, G);
    k_skip<<<2048, 256, 0, stream>>>(G, xskip, sw, sb, out_sk);

    // hop 1 (both mixprops)
    k_wcvt2<<<16384, 256, 0, stream>>>(mp1_gw, mp2_gw, Wb0, Wb1);
    k_gemm2g<<<256, 512, 0, stream>>>(G, G, Wb0, Wb1, G, mp1_gb, mp2_gb,
                                      H1, H1b, XW0a, XW0b);
    k_gcnfix<<<1024, 256, 0, stream>>>(XW0a, XW0b, G, A, dis1, inv1, dis2, inv2,
                                       mp1_gb, mp2_gb, H1, H1b);
    // hop 2 (both mixprops)
    k_wcvt2<<<16384, 256, 0, stream>>>(mp1_gw + MB16, mp2_gw + MB16, Wb0, Wb1);
    k_gemm2g<<<256, 512, 0, stream>>>(H1, H1b, Wb0, Wb1, G, mp1_gb + 4096, mp2_gb + 4096,
                                      H2, H2b, XW0a, XW0b);
    k_gcnfix<<<1024, 256, 0, stream>>>(XW0a, XW0b, G, A, dis1, inv1, dis2, inv2,
                                       mp1_gb + 4096, mp2_gb + 4096, H2, H2b);
    // fused channel-mix + residual + LN
    k_mix2ln<<<2048, 256, 0, stream>>>(G, H1, H2, H1b, H2b, mp1_mw, mp1_mb,
                                       mp2_mw, mp2_mb, x, Yb, part);
    k_lnnorm<<<2048, 256, 0, stream>>>(Yb, part, idxp, lnw, lnb, out_x);
}

// Round 7
// 671.024 us; speedup vs baseline: 1.5658x; 1.0725x over previous
//
#include <hip/hip_runtime.h>
#include <stdint.h>

typedef unsigned short u16;
typedef unsigned int   u32;
typedef __attribute__((ext_vector_type(4))) float f32x4;
typedef __attribute__((ext_vector_type(8))) short bf16x8;

__device__ __forceinline__ u16 f2bf(float f) {
    u32 i = __float_as_uint(f);
    u32 r = (i + 0x7fffu + ((i >> 16) & 1u)) >> 16;   // RNE
    return (u16)r;
}
__device__ __forceinline__ float bf2f(u16 u) {
    return __uint_as_float(((u32)u) << 16);
}
__device__ __forceinline__ u32 cvt2bf(float a, float b) {
    u32 r;
    asm("v_cvt_pk_bf16_f32 %0, %1, %2" : "=v"(r) : "v"(a), "v"(b));
    return r;
}

#define GLOAD16(g, l) __builtin_amdgcn_global_load_lds( \
    (const __attribute__((address_space(1))) void*)(g), \
    (__attribute__((address_space(3))) void*)(l), 16, 0, 0)

#define RAW_BARRIER()  asm volatile("s_barrier" ::: "memory")
#define VMCNT(n)       asm volatile("s_waitcnt vmcnt(" #n ")" ::: "memory")

// ---------------------------------------------------------------- prep: degrees
__global__ void k_prep(const float* __restrict__ A, float* dis1, float* inv1,
                       float* dis2, float* inv2)
{
    int r = threadIdx.x;
    if (r >= 128) return;
    int cc = 0, cr = 0;
    for (int j = 0; j < 128; ++j) {
        if (j == r) continue;
        if (A[(j << 7) + r] != 0.f) cc++;   // column count (mp1)
        if (A[(r << 7) + j] != 0.f) cr++;   // row count (mp2, A^T)
    }
    float d1 = 1.f + (float)cc, d2 = 1.f + (float)cr;
    dis1[r] = rsqrtf(d1); inv1[r] = 1.f / d1;
    dis2[r] = rsqrtf(d2); inv2[r] = 1.f / d2;
}

// ---------------------------------------------------------------- weight f32 -> bf16 (both mixprops, one hop)
__global__ __launch_bounds__(256)
void k_wcvt2(const float* __restrict__ W0, const float* __restrict__ W1,
             u16* __restrict__ Wb0, u16* __restrict__ Wb1)
{
    int half = blockIdx.x >> 13;                      // grid 16384: 8192 per matrix
    const float* W = half ? W1 : W0;
    u16* Wb = half ? Wb1 : Wb0;
    size_t e = ((size_t)(blockIdx.x & 8191) * 256 + threadIdx.x) * 8;
    f32x4 a = *(const f32x4*)(W + e);
    f32x4 b = *(const f32x4*)(W + e + 4);
    uint4 r;
    r.x = cvt2bf(a[0], a[1]); r.y = cvt2bf(a[2], a[3]);
    r.z = cvt2bf(b[0], b[1]); r.w = cvt2bf(b[2], b[3]);
    *(uint4*)(Wb + e) = r;
}

// ---------------------------------------------------------------- GEMM + fused GCN-self epilogue
// 256x256 tile, BK=64, 512 thr (8 waves 2x4), 2 LDS buffers x {A-k0,A-k1,B-k0,B-k1}
// 16KB regions. 4 phases/K-tile: {ds_read half | stage 1 region | vmcnt(8) |
// raw barrier | setprio 16xMFMA | raw barrier}. Stage plan: tile t: p1->A-k1(t+1),
// p2->B-k1(t+1) [other buffer], p3->A-k0(t+2), p4->B-k0(t+2) [same buffer, region
// free after p2]. Slot-XOR swizzle s^=(row>>1)&3 on both stage-src and read.
__global__ __launch_bounds__(512, 1)
void k_gemm2g(const u16* __restrict__ A0, const u16* __restrict__ A1,
              const u16* __restrict__ B0, const u16* __restrict__ B1,
              const u16* __restrict__ Gres,
              const float* __restrict__ gb0, const float* __restrict__ gb1,
              u16* __restrict__ Ha, u16* __restrict__ Hb,
              float* __restrict__ XW0a, float* __restrict__ XW0b)
{
    __shared__ alignas(16) u16 LDS[65536];     // 128 KB
    const int NT = 64;                          // K / BK = 4096 / 64
    const int tid  = threadIdx.x;
    const int lane = tid & 63;
    const int wid  = tid >> 6;
    const int wr = wid >> 2, wc = wid & 3;      // 2 x 4 wave grid, per-wave C 128x64

    // 256 WGs flat; bijective XCD swizzle
    const int bid = blockIdx.x;
    const int swz = (bid & 7) * 32 + (bid >> 3);
    const int z   = swz >> 7;
    const int rem = swz & 127;
    const int bm = (rem >> 4) * 256;            // 8 m-tiles
    const int bn = (rem & 15) * 256;            // 16 n-tiles

    const u16* Ap = (z ? A1 : A0) + (size_t)bm * 4096;
    const u16* Bp = (z ? B1 : B0) + (size_t)bn * 4096;

    // fragment LDS offsets within a 16KB region (row*32 + swizzled_slot*8)
    int aoff[8], boff[4];
    #pragma unroll
    for (int i = 0; i < 8; ++i) {
        int row = wr * 128 + i * 16 + (lane & 15);
        int sp  = (lane >> 4) ^ ((row >> 1) & 3);
        aoff[i] = row * 32 + sp * 8;
    }
    #pragma unroll
    for (int j = 0; j < 4; ++j) {
        int row = wc * 64 + j * 16 + (lane & 15);
        int sp  = (lane >> 4) ^ ((row >> 1) & 3);
        boff[j] = row * 32 + sp * 8;
    }

    // staging: 16KB region = 1024 chunks of 16B; thread does chunks {tid, tid+512}
    auto stageA = [&](int t, int kh) {
        if (t >= NT) return;
        const int kb = t * 64 + kh * 32;
        u16* dst = LDS + ((t & 1) << 15) + (kh << 13);
        #pragma unroll
        for (int h = 0; h < 2; ++h) {
            const int c = tid + h * 512;
            const int r = c >> 2;
            const int sl = (c & 3) ^ ((r >> 1) & 3);
            GLOAD16(Ap + (size_t)r * 4096 + kb + sl * 8, dst + c * 8);
        }
    };
    auto stageB = [&](int t, int kh) {
        if (t >= NT) return;
        const int kb = t * 64 + kh * 32;
        u16* dst = LDS + ((t & 1) << 15) + 16384 + (kh << 13);
        #pragma unroll
        for (int h = 0; h < 2; ++h) {
            const int c = tid + h * 512;
            const int r = c >> 2;
            const int sl = (c & 3) ^ ((r >> 1) & 3);
            GLOAD16(Bp + (size_t)r * 4096 + kb + sl * 8, dst + c * 8);
        }
    };

    f32x4 acc[8][4] = {};

    // prologue: tile0 all 4 regions + tile1 k0 regions
    stageA(0, 0); stageB(0, 0); stageA(0, 1); stageB(0, 1);
    stageA(1, 0); stageB(1, 0);
    VMCNT(0);
    RAW_BARRIER();

    for (int t = 0; t < NT; ++t) {
        const int bb = (t & 1) << 15;
        bf16x8 bfr[4];
        // ---- P1: kstep0, m0-3 (reads A-k0 m0-3 + B-k0 n0-3)
        {
            bf16x8 afr[4];
            #pragma unroll
            for (int i = 0; i < 4; ++i) afr[i] = *(const bf16x8*)(LDS + bb + aoff[i]);
            #pragma unroll
            for (int j = 0; j < 4; ++j) bfr[j] = *(const bf16x8*)(LDS + bb + 16384 + boff[j]);
            stageA(t + 1, 1);
            VMCNT(8);
            RAW_BARRIER();
            __builtin_amdgcn_s_setprio(1);
            #pragma unroll
            for (int i = 0; i < 4; ++i)
                #pragma unroll
                for (int j = 0; j < 4; ++j)
                    acc[i][j] = __builtin_amdgcn_mfma_f32_16x16x32_bf16(afr[i], bfr[j], acc[i][j], 0, 0, 0);
            __builtin_amdgcn_s_setprio(0);
            RAW_BARRIER();
        }
        // ---- P2: kstep0, m4-7 (reads A-k0 m4-7; B reused in regs)
        {
            bf16x8 afr[4];
            #pragma unroll
            for (int i = 0; i < 4; ++i) afr[i] = *(const bf16x8*)(LDS + bb + aoff[i + 4]);
            stageB(t + 1, 1);
            VMCNT(8);
            RAW_BARRIER();
            __builtin_amdgcn_s_setprio(1);
            #pragma unroll
            for (int i = 0; i < 4; ++i)
                #pragma unroll
                for (int j = 0; j < 4; ++j)
                    acc[i + 4][j] = __builtin_amdgcn_mfma_f32_16x16x32_bf16(afr[i], bfr[j], acc[i + 4][j], 0, 0, 0);
            __builtin_amdgcn_s_setprio(0);
            RAW_BARRIER();
        }
        // ---- P3: kstep1, m0-3 (reads A-k1 m0-3 + B-k1 n0-3)
        {
            bf16x8 afr[4];
            #pragma unroll
            for (int i = 0; i < 4; ++i) afr[i] = *(const bf16x8*)(LDS + bb + 8192 + aoff[i]);
            #pragma unroll
            for (int j = 0; j < 4; ++j) bfr[j] = *(const bf16x8*)(LDS + bb + 24576 + boff[j]);
            stageA(t + 2, 0);
            VMCNT(8);
            RAW_BARRIER();
            __builtin_amdgcn_s_setprio(1);
            #pragma unroll
            for (int i = 0; i < 4; ++i)
                #pragma unroll
                for (int j = 0; j < 4; ++j)
                    acc[i][j] = __builtin_amdgcn_mfma_f32_16x16x32_bf16(afr[i], bfr[j], acc[i][j], 0, 0, 0);
            __builtin_amdgcn_s_setprio(0);
            RAW_BARRIER();
        }
        // ---- P4: kstep1, m4-7
        {
            bf16x8 afr[4];
            #pragma unroll
            for (int i = 0; i < 4; ++i) afr[i] = *(const bf16x8*)(LDS + bb + 8192 + aoff[i + 4]);
            stageB(t + 2, 0);
            VMCNT(8);
            RAW_BARRIER();
            __builtin_amdgcn_s_setprio(1);
            #pragma unroll
            for (int i = 0; i < 4; ++i)
                #pragma unroll
                for (int j = 0; j < 4; ++j)
                    acc[i + 4][j] = __builtin_amdgcn_mfma_f32_16x16x32_bf16(afr[i], bfr[j], acc[i + 4][j], 0, 0, 0);
            __builtin_amdgcn_s_setprio(0);
            RAW_BARRIER();
        }
    }

    // ---------------- epilogue
    const int orow = (lane >> 4) * 4, ocol = lane & 15;
    const float* gbv = z ? gb1 : gb0;
    u16* H = z ? Hb : Ha;

    #pragma unroll
    for (int j = 0; j < 4; ++j) {
        const int o = bn + wc * 64 + j * 16 + ocol;
        const float gbo = gbv[o];
        #pragma unroll
        for (int i = 0; i < 8; ++i) {
            const int rbase = bm + wr * 128 + i * 16 + orow;
            #pragma unroll
            for (int v = 0; v < 4; ++v) {
                const size_t e = (size_t)(rbase + v) * 4096 + o;
                float g = bf2f(Gres[e]);
                H[e] = f2bf(__fmaf_rn(0.05f, g, acc[i][j][v] + gbo));
            }
        }
    }
    if (bm == 0 && wr == 0) {
        float* XW0 = z ? XW0b : XW0a;
        #pragma unroll
        for (int i = 0; i < 8; ++i) {
            #pragma unroll
            for (int j = 0; j < 4; ++j) {
                float* cp = XW0 + (size_t)(i * 16 + orow) * 4096 + (bn + wc * 64 + j * 16 + ocol);
                #pragma unroll
                for (int v = 0; v < 4; ++v)
                    cp[(size_t)v * 4096] = acc[i][j][v];
            }
        }
    }
}

// ---------------------------------------------------------------- GCN fixup rows < 128 (both problems)
__global__ __launch_bounds__(256)
void k_gcnfix(const float* __restrict__ XW0a, const float* __restrict__ XW0b,
              const u16* __restrict__ G, const float* __restrict__ Af,
              const float* __restrict__ dis1, const float* __restrict__ inv1,
              const float* __restrict__ dis2, const float* __restrict__ inv2,
              const float* __restrict__ gb0, const float* __restrict__ gb1,
              u16* __restrict__ Ha, u16* __restrict__ Hb)
{
    const int prob = blockIdx.x >> 9;          // 0: mp1 (A), 1: mp2 (A^T)
    const int rem  = blockIdx.x & 511;
    const int t4 = rem * 256 + threadIdx.x;
    const int r = t4 >> 10, og = (t4 & 1023) << 2;
    const float* XW0 = prob ? XW0b : XW0a;
    const float* dis = prob ? dis2 : dis1;
    const float* inv = prob ? inv2 : inv1;
    const float* gb  = prob ? gb1  : gb0;
    u16* H = prob ? Hb : Ha;

    const size_t e = ((size_t)r << 12) + og;
    f32x4 xw = *(const f32x4*)(XW0 + e);
    f32x4 s = {0.f, 0.f, 0.f, 0.f};
    for (int j = 0; j < 128; ++j) {
        float av = prob ? Af[(r << 7) + j] : Af[(j << 7) + r];
        float wv = ((av != 0.f) && (j != r)) ? dis[j] : 0.f;
        f32x4 xv = *(const f32x4*)(XW0 + ((size_t)j << 12) + og);
        #pragma unroll
        for (int q = 0; q < 4; ++q) s[q] = __fmaf_rn(wv, xv[q], s[q]);
    }
    const float iv = inv[r], dr = dis[r];
    f32x4 gb4 = *(const f32x4*)(gb + og);
    uint2 gv = *(const uint2*)(G + e);
    float g0 = __uint_as_float(gv.x << 16), g1 = __uint_as_float(gv.x & 0xffff0000u);
    float g2 = __uint_as_float(gv.y << 16), g3 = __uint_as_float(gv.y & 0xffff0000u);
    float y0 = __fmaf_rn(0.05f, g0, __fmaf_rn(dr, s[0], xw[0] * iv) + gb4[0]);
    float y1 = __fmaf_rn(0.05f, g1, __fmaf_rn(dr, s[1], xw[1] * iv) + gb4[1]);
    float y2 = __fmaf_rn(0.05f, g2, __fmaf_rn(dr, s[2], xw[2] * iv) + gb4[2]);
    float y3 = __fmaf_rn(0.05f, g3, __fmaf_rn(dr, s[3], xw[3] * iv) + gb4[3]);
    uint2 rr;
    rr.x = cvt2bf(y0, y1);
    rr.y = cvt2bf(y2, y3);
    *(uint2*)(H + e) = rr;
}

// ---------------------------------------------------------------- inception + gate (wave-balanced)
__device__ __forceinline__ constexpr int wbase_of(int k) {
    return k == 2 ? 0 : k == 3 ? 520 : k == 6 ? 1296 : 2840;
}
__device__ __forceinline__ constexpr int ob_of(int k) {
    return k == 2 ? 0 : k == 3 ? 8 : k == 6 ? 16 : 24;
}

template<int K_>
__device__ __forceinline__ void conv_phase(const float* __restrict__ xsb,
                                           const float* __restrict__ wfp,
                                           const float* __restrict__ wgp,
                                           float fb, float gb,
                                           u16* __restrict__ Gp)
{
    float accf[8], accg[8];
    #pragma unroll
    for (int i = 0; i < 8; ++i) { accf[i] = fb; accg[i] = gb; }
    for (int c = 0; c < 32; ++c) {
        float xw[24];
        const float* xr = xsb + c * 144;
        #pragma unroll
        for (int q = 0; q < 6; ++q) {
            f32x4 v = *(const f32x4*)(xr + q * 4);
            xw[q * 4 + 0] = v[0]; xw[q * 4 + 1] = v[1];
            xw[q * 4 + 2] = v[2]; xw[q * 4 + 3] = v[3];
        }
        float wfj[K_], wgj[K_];
        const float* wfc = wfp + c * K_;
        const float* wgc = wgp + c * K_;
        #pragma unroll
        for (int j = 0; j < K_; ++j) { wfj[j] = wfc[j]; wgj[j] = wgc[j]; }
        #pragma unroll
        for (int li = 0; li < 8; ++li) {
            #pragma unroll
            for (int j = 0; j < K_; ++j) {
                float xv = xw[li + 8 - (K_ - 1) + 2 * j];
                accf[li] = __fmaf_rn(xv, wfj[j], accf[li]);
                accg[li] = __fmaf_rn(xv, wgj[j], accg[li]);
            }
        }
    }
    u16 o8[8];
    #pragma unroll
    for (int i = 0; i < 8; ++i) {
        float e2 = __expf(2.f * accf[i]);
        float th = 1.f - __fdividef(2.f, e2 + 1.f);
        float sg = __fdividef(1.f, 1.f + __expf(-accg[i]));
        o8[i] = f2bf(th * sg);
    }
    uint4 u;
    u.x = o8[0] | ((u32)o8[1] << 16); u.y = o8[2] | ((u32)o8[3] << 16);
    u.z = o8[4] | ((u32)o8[5] << 16); u.w = o8[6] | ((u32)o8[7] << 16);
    *(uint4*)Gp = u;
}

template<int KA, int KB>
__device__ __forceinline__ void wave_pair(const float* __restrict__ xs,
                                          const float* __restrict__ wfl,
                                          const float* __restrict__ wgl,
                                          const float* __restrict__ fbl,
                                          const float* __restrict__ gbl,
                                          int oo, int lL, int b, int n,
                                          u16* __restrict__ G)
{
    {
        constexpr int BS = wbase_of(KA), ST = 32 * KA + 1, OB = ob_of(KA);
        const int o = OB + oo, l0 = lL * 8;
        conv_phase<KA>(xs + l0, wfl + BS + oo * ST, wgl + BS + oo * ST,
                       fbl[o], gbl[o],
                       G + (((size_t)(b * 32 + o) * 128 + n) * 128 + l0));
    }
    {
        constexpr int BS = wbase_of(KB), ST = 32 * KB + 1, OB = ob_of(KB);
        const int o = OB + oo, l0 = 64 + lL * 8;
        conv_phase<KB>(xs + l0, wfl + BS + oo * ST, wgl + BS + oo * ST,
                       fbl[o], gbl[o],
                       G + (((size_t)(b * 32 + o) * 128 + n) * 128 + l0));
    }
}

__global__ __launch_bounds__(256)
void k_incep(const float* __restrict__ x,
             const float* __restrict__ fw2p, const float* __restrict__ fw3p,
             const float* __restrict__ fw6p, const float* __restrict__ fw7p,
             const float* __restrict__ fb2p, const float* __restrict__ fb3p,
             const float* __restrict__ fb6p, const float* __restrict__ fb7p,
             const float* __restrict__ gw2p, const float* __restrict__ gw3p,
             const float* __restrict__ gw6p, const float* __restrict__ gw7p,
             const float* __restrict__ gb2p, const float* __restrict__ gb3p,
             const float* __restrict__ gb6p, const float* __restrict__ gb7p,
             u16* __restrict__ G)
{
    __shared__ alignas(16) float xs[32 * 144];
    __shared__ float wfl[4640], wgl[4640];
    __shared__ float fbl[32], gbl[32];
    const int tid = threadIdx.x;
    const int b = blockIdx.x >> 7, n = blockIdx.x & 127;

    for (int i = tid; i < 32 * 144; i += 256) xs[i] = 0.f;
    for (int g = tid; g < 4608; g += 256) {
        int rel, k, woff;
        const float *pf, *pg;
        if (g < 512)       { rel = g;        k = 2; woff = 0;    pf = fw2p; pg = gw2p; }
        else if (g < 1280) { rel = g - 512;  k = 3; woff = 520;  pf = fw3p; pg = gw3p; }
        else if (g < 2816) { rel = g - 1280; k = 6; woff = 1296; pf = fw6p; pg = gw6p; }
        else               { rel = g - 2816; k = 7; woff = 2840; pf = fw7p; pg = gw7p; }
        int ck = 32 * k;
        int oo = rel / ck, rem = rel % ck;
        int dst = woff + oo * (ck + 1) + rem;
        wfl[dst] = pf[rel];
        wgl[dst] = pg[rel];
    }
    if (tid < 32) {
        int br = tid >> 3, oo = tid & 7;
        const float* pf = br == 0 ? fb2p : br == 1 ? fb3p : br == 2 ? fb6p : fb7p;
        const float* pg = br == 0 ? gb2p : br == 1 ? gb3p : br == 2 ? gb6p : gb7p;
        fbl[tid] = pf[oo]; gbl[tid] = pg[oo];
    }
    __syncthreads();
    const float* xb = x + (size_t)b * 524288 + n * 128;
    for (int p = 0; p < 4; ++p) {
        int chunk = p * 256 + tid;
        int c = chunk >> 5, l4 = (chunk & 31) * 4;
        *(f32x4*)&xs[c * 144 + 8 + l4] = *(const f32x4*)(xb + (size_t)c * 16384 + l4);
    }
    __syncthreads();

    const int w = tid >> 6, lane = tid & 63;
    const int oo = lane >> 3, lL = lane & 7;
    switch (w) {
        case 0:  wave_pair<2, 7>(xs, wfl, wgl, fbl, gbl, oo, lL, b, n, G); break;
        case 1:  wave_pair<7, 2>(xs, wfl, wgl, fbl, gbl, oo, lL, b, n, G); break;
        case 2:  wave_pair<3, 6>(xs, wfl, wgl, fbl, gbl, oo, lL, b, n, G); break;
        default: wave_pair<6, 3>(xs, wfl, wgl, fbl, gbl, oo, lL, b, n, G); break;
    }
}

// ---------------------------------------------------------------- skip projection
__global__ __launch_bounds__(256)
void k_skip(const u16* __restrict__ G, const float* __restrict__ xskip,
            const float* __restrict__ sw, const float* __restrict__ sb,
            float* __restrict__ outp)
{
    __shared__ alignas(16) u16 Gs[4096];
    __shared__ float swl[64 * 33];
    __shared__ float sbl[64];
    const int tid = threadIdx.x;
    const int b = blockIdx.x >> 7, n = blockIdx.x & 127;
    const u16* gb_ = G + (size_t)b * 524288 + n * 128;
    for (int p = 0; p < 2; ++p) {
        int chunk = p * 256 + tid, c = chunk >> 4, l8 = (chunk & 15) * 8;
        *(uint4*)&Gs[c * 128 + l8] = *(const uint4*)(gb_ + (size_t)c * 16384 + l8);
    }
    for (int i = tid; i < 2048; i += 256) swl[(i >> 5) * 33 + (i & 31)] = sw[i];
    if (tid < 64) sbl[tid] = sb[tid];
    __syncthreads();
    const int sg = (tid & 15) * 4, l0 = (tid >> 4) * 8;
    float acc[4][8];
    #pragma unroll
    for (int si = 0; si < 4; ++si) {
        float bv = sbl[sg + si];
        #pragma unroll
        for (int li = 0; li < 8; ++li) acc[si][li] = bv;
    }
    for (int c = 0; c < 32; ++c) {
        uint4 gv = *(const uint4*)&Gs[c * 128 + l0];
        float g[8];
        g[0] = __uint_as_float(gv.x << 16); g[1] = __uint_as_float(gv.x & 0xffff0000u);
        g[2] = __uint_as_float(gv.y << 16); g[3] = __uint_as_float(gv.y & 0xffff0000u);
        g[4] = __uint_as_float(gv.z << 16); g[5] = __uint_as_float(gv.z & 0xffff0000u);
        g[6] = __uint_as_float(gv.w << 16); g[7] = __uint_as_float(gv.w & 0xffff0000u);
        #pragma unroll
        for (int si = 0; si < 4; ++si) {
            float wv = swl[(sg + si) * 33 + c];
            #pragma unroll
            for (int li = 0; li < 8; ++li) acc[si][li] = __fmaf_rn(g[li], wv, acc[si][li]);
        }
    }
    #pragma unroll
    for (int si = 0; si < 4; ++si) {
        size_t e = ((size_t)(b * 64 + sg + si) * 128 + n) * 128 + l0;
        f32x4 x0 = *(const f32x4*)(xskip + e);
        f32x4 x1 = *(const f32x4*)(xskip + e + 4);
        f32x4 r0, r1;
        r0[0] = acc[si][0] + x0[0]; r0[1] = acc[si][1] + x0[1];
        r0[2] = acc[si][2] + x0[2]; r0[3] = acc[si][3] + x0[3];
        r1[0] = acc[si][4] + x1[0]; r1[1] = acc[si][5] + x1[1];
        r1[2] = acc[si][6] + x1[2]; r1[3] = acc[si][7] + x1[3];
        *(f32x4*)(outp + e)     = r0;
        *(f32x4*)(outp + e + 4) = r1;
    }
}

// ---------------------------------------------------------------- fused mix1+mix2 + x-residual + LN partial sums
__global__ __launch_bounds__(256)
void k_mix2ln(const u16* __restrict__ G,
              const u16* __restrict__ H1, const u16* __restrict__ H2,
              const u16* __restrict__ H1b, const u16* __restrict__ H2b,
              const float* __restrict__ mw1, const float* __restrict__ mb1,
              const float* __restrict__ mw2, const float* __restrict__ mb2,
              const float* __restrict__ x,
              float* __restrict__ Y, float* __restrict__ partial)
{
    __shared__ alignas(16) u16 Gs[4096], H1s[4096], H2s[4096], H1bs[4096], H2bs[4096];
    __shared__ float wSg[32 * 33], wS11[32 * 33], wS12[32 * 33], wS21[32 * 33], wS22[32 * 33];
    __shared__ float mbl[32];
    const int tid = threadIdx.x;
    const int b = blockIdx.x >> 7, xn = blockIdx.x & 127;
    size_t base = (size_t)b * 524288 + xn * 128;
    for (int p = 0; p < 2; ++p) {
        int chunk = p * 256 + tid, c = chunk >> 4, l8 = (chunk & 15) * 8;
        size_t src = base + (size_t)c * 16384 + l8;
        *(uint4*)&Gs[c * 128 + l8]   = *(const uint4*)(G + src);
        *(uint4*)&H1s[c * 128 + l8]  = *(const uint4*)(H1 + src);
        *(uint4*)&H2s[c * 128 + l8]  = *(const uint4*)(H2 + src);
        *(uint4*)&H1bs[c * 128 + l8] = *(const uint4*)(H1b + src);
        *(uint4*)&H2bs[c * 128 + l8] = *(const uint4*)(H2b + src);
    }
    for (int i = tid; i < 1024; i += 256) {
        int o = i >> 5, c = i & 31;
        int d = o * 33 + c;
        wSg[d]  = mw1[o * 96 + c] + mw2[o * 96 + c];
        wS11[d] = mw1[o * 96 + 32 + c];
        wS12[d] = mw1[o * 96 + 64 + c];
        wS21[d] = mw2[o * 96 + 32 + c];
        wS22[d] = mw2[o * 96 + 64 + c];
    }
    if (tid < 32) mbl[tid] = mb1[tid] + mb2[tid];
    __syncthreads();
    const int og = (tid & 7) * 4, l0 = (tid >> 3) * 4;
    float acc[4][4];
    #pragma unroll
    for (int oi = 0; oi < 4; ++oi) {
        float bv = mbl[og + oi];
        acc[oi][0] = bv; acc[oi][1] = bv; acc[oi][2] = bv; acc[oi][3] = bv;
    }
    for (int c = 0; c < 32; ++c) {
        uint2 ga = *(const uint2*)&Gs[c * 128 + l0];
        uint2 h1 = *(const uint2*)&H1s[c * 128 + l0];
        uint2 h2 = *(const uint2*)&H2s[c * 128 + l0];
        uint2 j1 = *(const uint2*)&H1bs[c * 128 + l0];
        uint2 j2 = *(const uint2*)&H2bs[c * 128 + l0];
        float gv[4], v1[4], v2[4], u1[4], u2[4];
        gv[0] = __uint_as_float(ga.x << 16); gv[1] = __uint_as_float(ga.x & 0xffff0000u);
        gv[2] = __uint_as_float(ga.y << 16); gv[3] = __uint_as_float(ga.y & 0xffff0000u);
        v1[0] = __uint_as_float(h1.x << 16); v1[1] = __uint_as_float(h1.x & 0xffff0000u);
        v1[2] = __uint_as_float(h1.y << 16); v1[3] = __uint_as_float(h1.y & 0xffff0000u);
        v2[0] = __uint_as_float(h2.x << 16); v2[1] = __uint_as_float(h2.x & 0xffff0000u);
        v2[2] = __uint_as_float(h2.y << 16); v2[3] = __uint_as_float(h2.y & 0xffff0000u);
        u1[0] = __uint_as_float(j1.x << 16); u1[1] = __uint_as_float(j1.x & 0xffff0000u);
        u1[2] = __uint_as_float(j1.y << 16); u1[3] = __uint_as_float(j1.y & 0xffff0000u);
        u2[0] = __uint_as_float(j2.x << 16); u2[1] = __uint_as_float(j2.x & 0xffff0000u);
        u2[2] = __uint_as_float(j2.y << 16); u2[3] = __uint_as_float(j2.y & 0xffff0000u);
        #pragma unroll
        for (int oi = 0; oi < 4; ++oi) {
            int d = (og + oi) * 33 + c;
            float a0 = wSg[d], a1 = wS11[d], a2 = wS12[d], a3 = wS21[d], a4 = wS22[d];
            #pragma unroll
            for (int li = 0; li < 4; ++li)
                acc[oi][li] += gv[li] * a0 + v1[li] * a1 + v2[li] * a2
                             + u1[li] * a3 + u2[li] * a4;
        }
    }
    float s = 0.f, ss = 0.f;
    #pragma unroll
    for (int oi = 0; oi < 4; ++oi) {
        size_t e = ((size_t)(b * 32 + og + oi) * 128 + xn) * 128 + l0;
        f32x4 xv = *(const f32x4*)(x + e);
        f32x4 yv;
        #pragma unroll
        for (int li = 0; li < 4; ++li) {
            float y = acc[oi][li] + xv[li];
            yv[li] = y;
            s += y; ss += y * y;
        }
        *(f32x4*)(Y + e) = yv;
    }
    #pragma unroll
    for (int o = 32; o > 0; o >>= 1) {
        s  += __shfl_down(s,  o, 64);
        ss += __shfl_down(ss, o, 64);
    }
    __shared__ float sred[8];
    int w = tid >> 6;
    if ((tid & 63) == 0) { sred[w * 2] = s; sred[w * 2 + 1] = ss; }
    __syncthreads();
    if (tid == 0) {
        partial[blockIdx.x * 2]     = sred[0] + sred[2] + sred[4] + sred[6];
        partial[blockIdx.x * 2 + 1] = sred[1] + sred[3] + sred[5] + sred[7];
    }
}

// ---------------------------------------------------------------- LayerNorm finalize
__global__ __launch_bounds__(256)
void k_lnnorm(const float* __restrict__ Y,
              const float* __restrict__ partial, const int* __restrict__ idxp,
              const float* __restrict__ lnw, const float* __restrict__ lnb,
              float* __restrict__ outx)
{
    const int tid = threadIdx.x;
    const int b = blockIdx.x >> 7, chunk = blockIdx.x & 127;
    float s = 0.f, ss = 0.f;
    if (tid < 128) {
        s  = partial[(b * 128 + tid) * 2];
        ss = partial[(b * 128 + tid) * 2 + 1];
    }
    #pragma unroll
    for (int o = 32; o > 0; o >>= 1) {
        s  += __shfl_down(s,  o, 64);
        ss += __shfl_down(ss, o, 64);
    }
    __shared__ float sred[4];
    __shared__ float mv[2];
    if ((tid & 63) == 0 && tid < 128) { sred[(tid >> 6) * 2] = s; sred[(tid >> 6) * 2 + 1] = ss; }
    __syncthreads();
    if (tid == 0) {
        float S = sred[0] + sred[2], SS = sred[1] + sred[3];
        float mean = S * (1.f / 524288.f);
        float var = SS * (1.f / 524288.f) - mean * mean;
        mv[0] = mean; mv[1] = rsqrtf(var + 1e-5f);
    }
    __syncthreads();
    const float mean = mv[0], rstd = mv[1];
    #pragma unroll
    for (int q = 0; q < 4; ++q) {
        int ib = chunk * 4096 + q * 1024 + tid * 4;
        size_t e = (size_t)b * 524288 + ib;
        f32x4 yv = *(const f32x4*)(Y + e);
        int c = ib >> 14, xn = (ib >> 7) & 127, l = ib & 127;
        int ix = idxp[xn];
        size_t we = ((size_t)c * 128 + ix) * 128 + l;
        f32x4 wv = *(const f32x4*)(lnw + we);
        f32x4 bv = *(const f32x4*)(lnb + we);
        f32x4 r;
        #pragma unroll
        for (int j = 0; j < 4; ++j)
            r[j] = (yv[j] - mean) * rstd * wv[j] + bv[j];
        *(f32x4*)(outx + e) = r;
    }
}

// ---------------------------------------------------------------- launcher
extern "C" void kernel_launch(void* const* d_in, const int* in_sizes, int n_in,
                              void* d_out, int out_size, void* d_ws, size_t ws_size,
                              hipStream_t stream)
{
    (void)in_sizes; (void)n_in; (void)out_size; (void)ws_size;
    const float* x      = (const float*)d_in[0];
    const float* xskip  = (const float*)d_in[1];
    const float* A      = (const float*)d_in[2];
    const int*   idxp   = (const int*)d_in[3];
    const float* fw2p = (const float*)d_in[4];  const float* fb2p = (const float*)d_in[5];
    const float* fw3p = (const float*)d_in[6];  const float* fb3p = (const float*)d_in[7];
    const float* fw6p = (const float*)d_in[8];  const float* fb6p = (const float*)d_in[9];
    const float* fw7p = (const float*)d_in[10]; const float* fb7p = (const float*)d_in[11];
    const float* gw2p = (const float*)d_in[12]; const float* gb2p = (const float*)d_in[13];
    const float* gw3p = (const float*)d_in[14]; const float* gb3p = (const float*)d_in[15];
    const float* gw6p = (const float*)d_in[16]; const float* gb6p = (const float*)d_in[17];
    const float* gw7p = (const float*)d_in[18]; const float* gb7p = (const float*)d_in[19];
    const float* sw   = (const float*)d_in[20]; const float* sb   = (const float*)d_in[21];
    const float* mp1_gw = (const float*)d_in[22]; const float* mp1_gb = (const float*)d_in[23];
    const float* mp1_mw = (const float*)d_in[24]; const float* mp1_mb = (const float*)d_in[25];
    const float* mp2_gw = (const float*)d_in[26]; const float* mp2_gb = (const float*)d_in[27];
    const float* mp2_mw = (const float*)d_in[28]; const float* mp2_mb = (const float*)d_in[29];
    const float* lnw = (const float*)d_in[30]; const float* lnb = (const float*)d_in[31];

    char* wsb = (char*)d_ws;
    float* out_x  = (float*)d_out;
    float* out_sk = out_x + 8388608;

    const size_t MB16 = 16777216, MB33 = 33554432;
    u16*   G    = (u16*)(wsb);
    u16*   H1   = (u16*)(wsb + MB16);
    u16*   H1b  = (u16*)(wsb + 2 * MB16);
    u16*   H2   = (u16*)(wsb + 3 * MB16);
    u16*   H2b  = (u16*)(wsb + 4 * MB16);
    u16*   Wb0  = (u16*)(wsb + 5 * MB16);
    u16*   Wb1  = (u16*)(wsb + 5 * MB16 + MB33);
    float* Yb   = (float*)Wb0;                      // reuse after hop-2 GEMM
    float* XW0a = (float*)(wsb + 5 * MB16 + 2 * MB33);
    float* XW0b = (float*)(wsb + 5 * MB16 + 2 * MB33 + 2097152);
    float* part = (float*)(wsb + 5 * MB16 + 2 * MB33 + 4194304);
    float* dd   = (float*)(wsb + 5 * MB16 + 2 * MB33 + 4194304 + 16384);
    float *dis1 = dd, *inv1 = dd + 128, *dis2 = dd + 256, *inv2 = dd + 384;

    k_prep<<<1, 128, 0, stream>>>(A, dis1, inv1, dis2, inv2);
    k_incep<<<2048, 256, 0, stream>>>(x, fw2p, fw3p, fw6p, fw7p, fb2p, fb3p, fb6p, fb7p,
                                      gw2p, gw3p, gw6p, gw7p, gb2p, gb3p, gb6p, gb7p, G);
    k_skip<<<2048, 256, 0, stream>>>(G, xskip, sw, sb, out_sk);

    // hop 1 (both mixprops)
    k_wcvt2<<<16384, 256, 0, stream>>>(mp1_gw, mp2_gw, Wb0, Wb1);
    k_gemm2g<<<256, 512, 0, stream>>>(G, G, Wb0, Wb1, G, mp1_gb, mp2_gb,
                                      H1, H1b, XW0a, XW0b);
    k_gcnfix<<<1024, 256, 0, stream>>>(XW0a, XW0b, G, A, dis1, inv1, dis2, inv2,
                                       mp1_gb, mp2_gb, H1, H1b);
    // hop 2 (both mixprops)
    k_wcvt2<<<16384, 256, 0, stream>>>(mp1_gw + MB16, mp2_gw + MB16, Wb0, Wb1);
    k_gemm2g<<<256, 512, 0, stream>>>(H1, H1b, Wb0, Wb1, G, mp1_gb + 4096, mp2_gb + 4096,
                                      H2, H2b, XW0a, XW0b);
    k_gcnfix<<<1024, 256, 0, stream>>>(XW0a, XW0b, G, A, dis1, inv1, dis2, inv2,
                                       mp1_gb + 4096, mp2_gb + 4096, H2, H2b);
    // fused channel-mix + residual + LN
    k_mix2ln<<<2048, 256, 0, stream>>>(G, H1, H2, H1b, H2b, mp1_mw, mp1_mb,
                                       mp2_mw, mp2_mb, x, Yb, part);
    k_lnnorm<<<2048, 256, 0, stream>>>(Yb, part, idxp, lnw, lnb, out_x);
}